// Round 3
// baseline (564.537 us; speedup 1.0000x reference)
//
#include <hip/hip_runtime.h>
#include <hip/hip_bf16.h>

#define NDT 30000
#define NOD 10000
#define NE1 500000
#define NE2 300000
#define NEL 200000

// ---------------- workspace layout (float units) ----------------
static constexpr size_t F_XDT    = 0;
static constexpr size_t F_XOD    = F_XDT + (size_t)NDT*128;
static constexpr size_t F_OD1_WL = F_XOD + (size_t)NOD*64;
static constexpr size_t F_OD1_WR = F_OD1_WL + 16384;
static constexpr size_t F_OD1_B  = F_OD1_WR + 16384;
static constexpr size_t F_OD2_WL = F_OD1_B + 128;
static constexpr size_t F_OD2_WR = F_OD2_WL + 16384;
static constexpr size_t F_OD2_B  = F_OD2_WR + 8192;
static constexpr size_t F_OD3_WL = F_OD2_B + 128;
static constexpr size_t F_OD3_WR = F_OD3_WL + 16384;
static constexpr size_t F_OD3_B  = F_OD3_WR + 16384;
static constexpr size_t F_OD_LW  = F_OD3_B + 128;
static constexpr size_t F_OD_LB  = F_OD_LW + 8192;
static constexpr size_t F_DT1_WL = F_OD_LB + 64;
static constexpr size_t F_DT1_WR = F_DT1_WL + 16384;
static constexpr size_t F_DT1_B  = F_DT1_WR + 16384;
static constexpr size_t F_DT2_WL = F_DT1_B + 128;
static constexpr size_t F_DT2_WR = F_DT2_WL + 16384;
static constexpr size_t F_DT2_B  = F_DT2_WR + 16384;
static constexpr size_t F_DT_LW  = F_DT2_B + 128;
static constexpr size_t F_DT_LB  = F_DT_LW + 8192;
static constexpr size_t F_DEC_W1 = F_DT_LB + 64;
static constexpr size_t F_DEC_B1 = F_DEC_W1 + 8192;
static constexpr size_t F_DEC_W2 = F_DEC_B1 + 64;
static constexpr size_t F_DEC_B2 = F_DEC_W2 + 64;
static constexpr size_t F_WOD    = F_DEC_B2 + 4;
static constexpr size_t F_WDT    = F_WOD + 8192;
static constexpr size_t F_BFUSE  = F_WDT + 8192;
static constexpr size_t F_BUFA   = F_BFUSE + 64;              // agg_x, later agg_d
static constexpr size_t F_BUFH   = F_BUFA + (size_t)NDT*128;  // h, later d2
static constexpr size_t F_BUFD   = F_BUFH + (size_t)NDT*128;  // d1
static constexpr size_t F_AGGH   = F_BUFD + (size_t)NDT*128;
static constexpr size_t F_OD2    = F_AGGH + (size_t)NOD*128;
static constexpr size_t F_OD3    = F_OD2 + (size_t)NOD*128;
static constexpr size_t F_POD    = F_OD3 + (size_t)NOD*128;
static constexpr size_t F_PDT    = F_POD + (size_t)NOD*64;
static constexpr size_t F_END    = F_PDT + (size_t)NDT*64;
// int region (indices into int* base = (int*)(ws + F_END))
static constexpr size_t I_CNT_DT = 0;        // 30000
static constexpr size_t I_CNT_OD = 30000;    // 10000  (adjacent -> one memset)
static constexpr size_t I_RS_DT  = 40000;    // 30001 (+pad)
static constexpr size_t I_RS_OD  = 70004;    // 10001 (+pad)
static constexpr size_t I_CUR_DT = 80008;    // 30000
static constexpr size_t I_CUR_OD = 110008;   // 10000
static constexpr size_t I_SRC_DT = 120008;   // 500000
static constexpr size_t I_SRC_OD = 620008;   // 300000
static constexpr size_t I_FLAG   = 920008;   // 1 (1 = inputs are f32, 0 = packed bf16)

// ---------------- input dtype detection ----------------
// f32 N(0,1) data: exponent field of each u32 in (97,157) essentially always.
// packed-bf16 data: u32 exponent field comes from low-exponent+mantissa bits
// of the high bf16 -> mostly outside that range. Vote over 64 words.
__global__ void detect_dtype(const unsigned* __restrict__ x, int* flag) {
    unsigned w = x[threadIdx.x & 63];
    int e = (w >> 23) & 0xFF;
    bool ok = (e > 97) && (e < 157);
    unsigned long long m = __ballot(ok);
    if (threadIdx.x == 0) *flag = (__popcll(m) >= 48) ? 1 : 0;
}

// ---------------- input -> fp32 staging (copy or bf16 expand) ----------------
#define NCONV 25
struct ConvArgs {
    const void* src[NCONV];
    float* dst[NCONV];
    int len[NCONV];
    int boff[NCONV + 1];
};

__global__ __launch_bounds__(256) void convert_all(ConvArgs a, const int* __restrict__ flag) {
    int b = blockIdx.x;
    int ti = 0;
    while (b >= a.boff[ti + 1]) ti++;
    int local = b - a.boff[ti];
    float* d = a.dst[ti];
    int n = a.len[ti];
    int base = local * 1024 + threadIdx.x;
    if (*flag) {
        const float* s = (const float*)a.src[ti];
#pragma unroll
        for (int k = 0; k < 4; k++) {
            int i = base + k * 256;
            if (i < n) d[i] = s[i];
        }
    } else {
        const unsigned short* s = (const unsigned short*)a.src[ti];
#pragma unroll
        for (int k = 0; k < 4; k++) {
            int i = base + k * 256;
            if (i < n) d[i] = __uint_as_float(((unsigned)s[i]) << 16);
        }
    }
}

// ---------------- CSR build ----------------
__global__ __launch_bounds__(256) void count_edges(const int* __restrict__ c1,
                                                   const int* __restrict__ rev_dst,
                                                   int* cnt_dt, int* cnt_od) {
    int i = blockIdx.x * 256 + threadIdx.x;
    if (i < NE1) atomicAdd(&cnt_dt[c1[i]], 1);
    if (i < NE2) atomicAdd(&cnt_od[rev_dst[i]], 1);
}

__global__ __launch_bounds__(1024) void scan2(const int* cnt_dt, int* rs_dt, int* cur_dt,
                                              const int* cnt_od, int* rs_od, int* cur_od) {
    __shared__ int s[1024];
    const int* cnt; int* rs; int* cur; int n;
    if (blockIdx.x == 0) { cnt = cnt_dt; rs = rs_dt; cur = cur_dt; n = NDT; }
    else                 { cnt = cnt_od; rs = rs_od; cur = cur_od; n = NOD; }
    int t = threadIdx.x;
    int carry = 0;
    for (int base = 0; base < n; base += 1024) {
        int v = (base + t < n) ? cnt[base + t] : 0;
        s[t] = v; __syncthreads();
        for (int off = 1; off < 1024; off <<= 1) {
            int x = (t >= off) ? s[t - off] : 0;
            __syncthreads();
            s[t] += x;
            __syncthreads();
        }
        int excl = s[t] - v + carry;
        if (base + t < n) { rs[base + t] = excl; cur[base + t] = excl; }
        carry += s[1023];
        __syncthreads();
    }
    if (t == 0) rs[n] = carry;
}

__global__ __launch_bounds__(256) void fill_edges(const int* __restrict__ r1, const int* __restrict__ c1,
                                                  const int* __restrict__ rev_src, const int* __restrict__ rev_dst,
                                                  int* cur_dt, int* srcs_dt, int* cur_od, int* srcs_od) {
    int i = blockIdx.x * 256 + threadIdx.x;
    if (i < NE1) { int p = atomicAdd(&cur_dt[c1[i]], 1); srcs_dt[p] = r1[i]; }
    if (i < NE2) { int p = atomicAdd(&cur_od[rev_dst[i]], 1); srcs_od[p] = rev_src[i]; }
}

// ---------------- segment mean (gather, dim=128) ----------------
__global__ __launch_bounds__(128) void seg_mean(const float* __restrict__ X,
                                                const int* __restrict__ rs,
                                                const int* __restrict__ srcs,
                                                float* __restrict__ out) {
    int b = blockIdx.x;
    int t = threadIdx.x;
    int start = rs[b], end = rs[b + 1];
    float a0 = 0.f, a1 = 0.f;
    int j = start;
    for (; j + 1 < end; j += 2) {
        int s0 = srcs[j], s1 = srcs[j + 1];
        a0 += X[(size_t)s0 * 128 + t];
        a1 += X[(size_t)s1 * 128 + t];
    }
    if (j < end) a0 += X[(size_t)srcs[j] * 128 + t];
    int deg = end - start;
    out[(size_t)b * 128 + t] = deg > 0 ? (a0 + a1) / (float)deg : 0.f;
}

// ---------------- sage layer: out = relu(A1@W1 + A2@W2 + b), N=128 ----------------
__global__ __launch_bounds__(256) void sage_layer(const float* __restrict__ A1, const float* __restrict__ W1,
                                                  const float* __restrict__ A2, const float* __restrict__ W2,
                                                  int K2, const float* __restrict__ bias,
                                                  float* __restrict__ out, int M) {
    __shared__ __align__(16) float As[32 * 132];
    __shared__ __align__(16) float Ws[64 * 128];
    int t = threadIdx.x;
    int tx = t & 31, ty = t >> 5;
    int mb = blockIdx.x * 32;
    float acc[4][4] = {};
    for (int phase = 0; phase < 2; ++phase) {
        const float* A = phase ? A2 : A1;
        const float* Wp = phase ? W2 : W1;
        int K = phase ? K2 : 128;
        int ksh = (K == 128) ? 7 : 6;
        int total = 32 * K;
        for (int idx = t * 4; idx < total; idx += 1024) {
            int row = idx >> ksh, k = idx & (K - 1);
            int m = mb + row; if (m > M - 1) m = M - 1;
            *(float4*)(As + row * 132 + k) = *(const float4*)(A + (size_t)m * K + k);
        }
        for (int kc = 0; kc < K; kc += 64) {
            for (int idx = t * 4; idx < 64 * 128; idx += 1024) {
                int kk = idx >> 7, n = idx & 127;
                *(float4*)(Ws + kk * 128 + n) = *(const float4*)(Wp + (size_t)(kc + kk) * 128 + n);
            }
            __syncthreads();
            for (int k0 = 0; k0 < 64; k0 += 4) {
                float4 av0 = *(const float4*)(As + (ty * 4 + 0) * 132 + kc + k0);
                float4 av1 = *(const float4*)(As + (ty * 4 + 1) * 132 + kc + k0);
                float4 av2 = *(const float4*)(As + (ty * 4 + 2) * 132 + kc + k0);
                float4 av3 = *(const float4*)(As + (ty * 4 + 3) * 132 + kc + k0);
                const float* a0 = (const float*)&av0;
                const float* a1 = (const float*)&av1;
                const float* a2 = (const float*)&av2;
                const float* a3 = (const float*)&av3;
#pragma unroll
                for (int kk = 0; kk < 4; kk++) {
                    float4 wv = *(const float4*)(Ws + (k0 + kk) * 128 + tx * 4);
                    float x0 = a0[kk], x1 = a1[kk], x2 = a2[kk], x3 = a3[kk];
                    acc[0][0] = fmaf(x0, wv.x, acc[0][0]); acc[0][1] = fmaf(x0, wv.y, acc[0][1]);
                    acc[0][2] = fmaf(x0, wv.z, acc[0][2]); acc[0][3] = fmaf(x0, wv.w, acc[0][3]);
                    acc[1][0] = fmaf(x1, wv.x, acc[1][0]); acc[1][1] = fmaf(x1, wv.y, acc[1][1]);
                    acc[1][2] = fmaf(x1, wv.z, acc[1][2]); acc[1][3] = fmaf(x1, wv.w, acc[1][3]);
                    acc[2][0] = fmaf(x2, wv.x, acc[2][0]); acc[2][1] = fmaf(x2, wv.y, acc[2][1]);
                    acc[2][2] = fmaf(x2, wv.z, acc[2][2]); acc[2][3] = fmaf(x2, wv.w, acc[2][3]);
                    acc[3][0] = fmaf(x3, wv.x, acc[3][0]); acc[3][1] = fmaf(x3, wv.y, acc[3][1]);
                    acc[3][2] = fmaf(x3, wv.z, acc[3][2]); acc[3][3] = fmaf(x3, wv.w, acc[3][3]);
                }
            }
            __syncthreads();
        }
    }
    float4 bv = *(const float4*)(bias + tx * 4);
#pragma unroll
    for (int j = 0; j < 4; j++) {
        int m = mb + ty * 4 + j;
        if (m < M) {
            float4 r;
            r.x = fmaxf(acc[j][0] + bv.x, 0.f);
            r.y = fmaxf(acc[j][1] + bv.y, 0.f);
            r.z = fmaxf(acc[j][2] + bv.z, 0.f);
            r.w = fmaxf(acc[j][3] + bv.w, 0.f);
            *(float4*)(out + (size_t)m * 128 + tx * 4) = r;
        }
    }
}

// ---------------- linear: out[M,64] = A[M,128] @ W[128,64] ----------------
__global__ __launch_bounds__(256) void lin_gemm(const float* __restrict__ A, const float* __restrict__ W,
                                                float* __restrict__ out, int M) {
    __shared__ __align__(16) float Ws[128 * 64];
    __shared__ __align__(16) float As[64 * 68];
    int t = threadIdx.x;
    int tx = t & 15, ty = t >> 4;
    int mb = blockIdx.x * 64;
    float acc[4][4] = {};
    for (int idx = t * 4; idx < 128 * 64; idx += 1024)
        *(float4*)(Ws + idx) = *(const float4*)(W + idx);
    for (int kc = 0; kc < 128; kc += 64) {
        __syncthreads();
        for (int idx = t * 4; idx < 64 * 64; idx += 1024) {
            int row = idx >> 6, k = idx & 63;
            int m = mb + row; if (m > M - 1) m = M - 1;
            *(float4*)(As + row * 68 + k) = *(const float4*)(A + (size_t)m * 128 + kc + k);
        }
        __syncthreads();
        for (int k0 = 0; k0 < 64; k0 += 4) {
            float4 av0 = *(const float4*)(As + (ty * 4 + 0) * 68 + k0);
            float4 av1 = *(const float4*)(As + (ty * 4 + 1) * 68 + k0);
            float4 av2 = *(const float4*)(As + (ty * 4 + 2) * 68 + k0);
            float4 av3 = *(const float4*)(As + (ty * 4 + 3) * 68 + k0);
            const float* a0 = (const float*)&av0;
            const float* a1 = (const float*)&av1;
            const float* a2 = (const float*)&av2;
            const float* a3 = (const float*)&av3;
#pragma unroll
            for (int kk = 0; kk < 4; kk++) {
                float4 wv = *(const float4*)(Ws + (kc + k0 + kk) * 64 + tx * 4);
                float x0 = a0[kk], x1 = a1[kk], x2 = a2[kk], x3 = a3[kk];
                acc[0][0] = fmaf(x0, wv.x, acc[0][0]); acc[0][1] = fmaf(x0, wv.y, acc[0][1]);
                acc[0][2] = fmaf(x0, wv.z, acc[0][2]); acc[0][3] = fmaf(x0, wv.w, acc[0][3]);
                acc[1][0] = fmaf(x1, wv.x, acc[1][0]); acc[1][1] = fmaf(x1, wv.y, acc[1][1]);
                acc[1][2] = fmaf(x1, wv.z, acc[1][2]); acc[1][3] = fmaf(x1, wv.w, acc[1][3]);
                acc[2][0] = fmaf(x2, wv.x, acc[2][0]); acc[2][1] = fmaf(x2, wv.y, acc[2][1]);
                acc[2][2] = fmaf(x2, wv.z, acc[2][2]); acc[2][3] = fmaf(x2, wv.w, acc[2][3]);
                acc[3][0] = fmaf(x3, wv.x, acc[3][0]); acc[3][1] = fmaf(x3, wv.y, acc[3][1]);
                acc[3][2] = fmaf(x3, wv.z, acc[3][2]); acc[3][3] = fmaf(x3, wv.w, acc[3][3]);
            }
        }
    }
#pragma unroll
    for (int j = 0; j < 4; j++) {
        int m = mb + ty * 4 + j;
        if (m < M) {
            float4 r = { acc[j][0], acc[j][1], acc[j][2], acc[j][3] };
            *(float4*)(out + (size_t)m * 64 + tx * 4) = r;
        }
    }
}

// ---------------- decoder weight fusion ----------------
__global__ __launch_bounds__(256) void fuse_dec(const float* __restrict__ od_lw, const float* __restrict__ od_lb,
                                                const float* __restrict__ dt_lw, const float* __restrict__ dt_lb,
                                                const float* __restrict__ w1, const float* __restrict__ b1,
                                                float* Wod, float* Wdt, float* bfuse) {
    int i = blockIdx.x * 256 + threadIdx.x;
    if (i < 8192) {
        int r = i >> 6, p = i & 63;
        float s = 0.f;
        for (int j = 0; j < 64; j++) s = fmaf(od_lw[r * 64 + j], w1[j * 64 + p], s);
        Wod[i] = s;
    } else if (i < 16384) {
        int q = i - 8192, r = q >> 6, p = q & 63;
        float s = 0.f;
        for (int j = 0; j < 64; j++) s = fmaf(dt_lw[r * 64 + j], w1[(64 + j) * 64 + p], s);
        Wdt[q] = s;
    } else if (i < 16448) {
        int p = i - 16384;
        float s = b1[p];
        for (int j = 0; j < 64; j++) {
            s = fmaf(od_lb[j], w1[j * 64 + p], s);
            s = fmaf(dt_lb[j], w1[(64 + j) * 64 + p], s);
        }
        bfuse[p] = s;
    }
}

// ---------------- decoder (FLOAT32 output) ----------------
__global__ __launch_bounds__(256) void decode(const float* __restrict__ P_od, const float* __restrict__ P_dt,
                                              const int* __restrict__ el_src, const int* __restrict__ el_dst,
                                              const float* __restrict__ bfuse, const float* __restrict__ w2,
                                              const float* __restrict__ b2v, float* __restrict__ out) {
    __shared__ __align__(16) float bf[64];
    __shared__ __align__(16) float w2s[64];
    int t = threadIdx.x;
    if (t < 64) { bf[t] = bfuse[t]; w2s[t] = w2[t]; }
    __syncthreads();
    int e = blockIdx.x * 256 + t;
    if (e >= NEL) return;
    const float4* po = (const float4*)(P_od + (size_t)el_src[e] * 64);
    const float4* pt = (const float4*)(P_dt + (size_t)el_dst[e] * 64);
    float acc = 0.f;
#pragma unroll 4
    for (int c = 0; c < 16; c++) {
        float4 a = po[c], b = pt[c];
        float4 bb = *(const float4*)&bf[c * 4];
        float4 ww = *(const float4*)&w2s[c * 4];
        acc = fmaf(fmaxf(a.x + b.x + bb.x, 0.f), ww.x, acc);
        acc = fmaf(fmaxf(a.y + b.y + bb.y, 0.f), ww.y, acc);
        acc = fmaf(fmaxf(a.z + b.z + bb.z, 0.f), ww.z, acc);
        acc = fmaf(fmaxf(a.w + b.w + bb.w, 0.f), ww.w, acc);
    }
    float z = acc + b2v[0];
    out[e] = 1.f / (1.f + __expf(-z));
}

// ---------------- launch ----------------
extern "C" void kernel_launch(void* const* d_in, const int* in_sizes, int n_in,
                              void* d_out, int out_size, void* d_ws, size_t ws_size,
                              hipStream_t stream) {
    float* W = (float*)d_ws;
    int* I = (int*)(W + F_END);

    const int* ei = (const int*)d_in[2];
    const int* r1 = ei;
    const int* c1 = ei + NE1;
    const int* rev_src = (const int*)d_in[3];
    const int* rev_dst = (const int*)d_in[4];
    const int* el_src = (const int*)d_in[5];
    const int* el_dst = (const int*)d_in[6];

    // zero edge counters (cnt_dt + cnt_od adjacent)
    hipMemsetAsync(I + I_CNT_DT, 0, (NDT + NOD) * sizeof(int), stream);

    // detect whether float inputs are f32-stored or packed bf16
    detect_dtype<<<1, 64, 0, stream>>>((const unsigned*)d_in[0], I + I_FLAG);

    // stage all float tensors into fp32 workspace
    ConvArgs ca;
    const int iidx[NCONV] = {0,1, 7,8,9, 10,11,12, 13,14,15, 16,17, 18,19,20, 21,22,23, 24,25, 26,27,28,29};
    const size_t foff[NCONV] = {F_XDT, F_XOD, F_OD1_WL, F_OD1_WR, F_OD1_B, F_OD2_WL, F_OD2_WR, F_OD2_B,
                                F_OD3_WL, F_OD3_WR, F_OD3_B, F_OD_LW, F_OD_LB, F_DT1_WL, F_DT1_WR, F_DT1_B,
                                F_DT2_WL, F_DT2_WR, F_DT2_B, F_DT_LW, F_DT_LB, F_DEC_W1, F_DEC_B1, F_DEC_W2, F_DEC_B2};
    const int lens[NCONV] = {NDT * 128, NOD * 64, 16384, 16384, 128, 16384, 8192, 128,
                             16384, 16384, 128, 8192, 64, 16384, 16384, 128,
                             16384, 16384, 128, 8192, 64, 8192, 64, 64, 1};
    int btot = 0;
    for (int i = 0; i < NCONV; i++) {
        ca.src[i] = d_in[iidx[i]];
        ca.dst[i] = W + foff[i];
        ca.len[i] = lens[i];
        ca.boff[i] = btot;
        btot += (lens[i] + 1023) / 1024;
    }
    ca.boff[NCONV] = btot;
    convert_all<<<btot, 256, 0, stream>>>(ca, I + I_FLAG);

    // CSR build for both graphs
    count_edges<<<(NE1 + 255) / 256, 256, 0, stream>>>(c1, rev_dst, I + I_CNT_DT, I + I_CNT_OD);
    scan2<<<2, 1024, 0, stream>>>(I + I_CNT_DT, I + I_RS_DT, I + I_CUR_DT,
                                  I + I_CNT_OD, I + I_RS_OD, I + I_CUR_OD);
    fill_edges<<<(NE1 + 255) / 256, 256, 0, stream>>>(r1, c1, rev_src, rev_dst,
                                                      I + I_CUR_DT, I + I_SRC_DT,
                                                      I + I_CUR_OD, I + I_SRC_OD);

    // decoder weight fusion (independent)
    fuse_dec<<<(16448 + 255) / 256, 256, 0, stream>>>(W + F_OD_LW, W + F_OD_LB, W + F_DT_LW, W + F_DT_LB,
                                                      W + F_DEC_W1, W + F_DEC_B1,
                                                      W + F_WOD, W + F_WDT, W + F_BFUSE);

    // agg_x = segmean(x_dt) over ei_dt  -> BUFA
    seg_mean<<<NDT, 128, 0, stream>>>(W + F_XDT, I + I_RS_DT, I + I_SRC_DT, W + F_BUFA);
    // h  = relu(agg_x@od1_wl + x_dt@od1_wr + b) -> BUFH
    sage_layer<<<(NDT + 31) / 32, 256, 0, stream>>>(W + F_BUFA, W + F_OD1_WL, W + F_XDT, W + F_OD1_WR, 128,
                                                    W + F_OD1_B, W + F_BUFH, NDT);
    // d1 = relu(agg_x@dt1_wl + x_dt@dt1_wr + b) -> BUFD
    sage_layer<<<(NDT + 31) / 32, 256, 0, stream>>>(W + F_BUFA, W + F_DT1_WL, W + F_XDT, W + F_DT1_WR, 128,
                                                    W + F_DT1_B, W + F_BUFD, NDT);
    // agg_h = segmean(h) over ei_rev -> AGGH
    seg_mean<<<NOD, 128, 0, stream>>>(W + F_BUFH, I + I_RS_OD, I + I_SRC_OD, W + F_AGGH);
    // od2 = relu(agg_h@od2_wl + x_od@od2_wr + b)
    sage_layer<<<(NOD + 31) / 32, 256, 0, stream>>>(W + F_AGGH, W + F_OD2_WL, W + F_XOD, W + F_OD2_WR, 64,
                                                    W + F_OD2_B, W + F_OD2, NOD);
    // od3 = relu(agg_h@od3_wl + od2@od3_wr + b)
    sage_layer<<<(NOD + 31) / 32, 256, 0, stream>>>(W + F_AGGH, W + F_OD3_WL, W + F_OD2, W + F_OD3_WR, 128,
                                                    W + F_OD3_B, W + F_OD3, NOD);
    // agg_d = segmean(d1) over ei_dt -> BUFA (agg_x dead)
    seg_mean<<<NDT, 128, 0, stream>>>(W + F_BUFD, I + I_RS_DT, I + I_SRC_DT, W + F_BUFA);
    // d2 = relu(agg_d@dt2_wl + d1@dt2_wr + b) -> BUFH (h dead)
    sage_layer<<<(NDT + 31) / 32, 256, 0, stream>>>(W + F_BUFA, W + F_DT2_WL, W + F_BUFD, W + F_DT2_WR, 128,
                                                    W + F_DT2_B, W + F_BUFH, NDT);
    // P_od = od3 @ Wod ; P_dt = d2 @ Wdt
    lin_gemm<<<(NOD + 63) / 64, 256, 0, stream>>>(W + F_OD3, W + F_WOD, W + F_POD, NOD);
    lin_gemm<<<(NDT + 63) / 64, 256, 0, stream>>>(W + F_BUFH, W + F_WDT, W + F_PDT, NDT);
    // decoder
    decode<<<(NEL + 255) / 256, 256, 0, stream>>>(W + F_POD, W + F_PDT, el_src, el_dst,
                                                  W + F_BFUSE, W + F_DEC_W2, W + F_DEC_B2,
                                                  (float*)d_out);
}

// Round 4
// 536.149 us; speedup vs baseline: 1.0529x; 1.0529x over previous
//
#include <hip/hip_runtime.h>
#include <hip/hip_bf16.h>

#define NDT 30000
#define NOD 10000
#define NE1 500000
#define NE2 300000
#define NEL 200000

// ---------------- workspace layout (float units) ----------------
static constexpr size_t F_XDT    = 0;
static constexpr size_t F_XOD    = F_XDT + (size_t)NDT*128;
static constexpr size_t F_OD1_WL = F_XOD + (size_t)NOD*64;
static constexpr size_t F_OD1_WR = F_OD1_WL + 16384;
static constexpr size_t F_OD1_B  = F_OD1_WR + 16384;
static constexpr size_t F_OD2_WL = F_OD1_B + 128;
static constexpr size_t F_OD2_WR = F_OD2_WL + 16384;
static constexpr size_t F_OD2_B  = F_OD2_WR + 8192;
static constexpr size_t F_OD3_WL = F_OD2_B + 128;
static constexpr size_t F_OD3_WR = F_OD3_WL + 16384;
static constexpr size_t F_OD3_B  = F_OD3_WR + 16384;
static constexpr size_t F_OD_LW  = F_OD3_B + 128;
static constexpr size_t F_OD_LB  = F_OD_LW + 8192;
static constexpr size_t F_DT1_WL = F_OD_LB + 64;
static constexpr size_t F_DT1_WR = F_DT1_WL + 16384;
static constexpr size_t F_DT1_B  = F_DT1_WR + 16384;
static constexpr size_t F_DT2_WL = F_DT1_B + 128;
static constexpr size_t F_DT2_WR = F_DT2_WL + 16384;
static constexpr size_t F_DT2_B  = F_DT2_WR + 16384;
static constexpr size_t F_DT_LW  = F_DT2_B + 128;
static constexpr size_t F_DT_LB  = F_DT_LW + 8192;
static constexpr size_t F_DEC_W1 = F_DT_LB + 64;
static constexpr size_t F_DEC_B1 = F_DEC_W1 + 8192;
static constexpr size_t F_DEC_W2 = F_DEC_B1 + 64;
static constexpr size_t F_DEC_B2 = F_DEC_W2 + 64;
static constexpr size_t F_WOD    = F_DEC_B2 + 4;
static constexpr size_t F_WDT    = F_WOD + 8192;
static constexpr size_t F_BFUSE  = F_WDT + 8192;
static constexpr size_t F_BUFA   = F_BFUSE + 64;              // agg_x, later agg_d
static constexpr size_t F_BUFH   = F_BUFA + (size_t)NDT*128;  // h, later d2
static constexpr size_t F_BUFD   = F_BUFH + (size_t)NDT*128;  // d1
static constexpr size_t F_AGGH   = F_BUFD + (size_t)NDT*128;
static constexpr size_t F_OD2    = F_AGGH + (size_t)NOD*128;
static constexpr size_t F_OD3    = F_OD2 + (size_t)NOD*128;
static constexpr size_t F_POD    = F_OD3 + (size_t)NOD*128;
static constexpr size_t F_PDT    = F_POD + (size_t)NOD*64;
static constexpr size_t F_END    = F_PDT + (size_t)NDT*64;
// int region (indices into int* base = (int*)(ws + F_END))
static constexpr size_t I_CNT_DT = 0;        // 30000
static constexpr size_t I_CNT_OD = 30000;    // 10000  (adjacent -> one memset)
static constexpr size_t I_RS_DT  = 40000;    // 30001 (+pad)
static constexpr size_t I_RS_OD  = 70004;    // 10001 (+pad)
static constexpr size_t I_CUR_DT = 80008;    // 30000
static constexpr size_t I_CUR_OD = 110008;   // 10000
static constexpr size_t I_SRC_DT = 120008;   // 500000
static constexpr size_t I_SRC_OD = 620008;   // 300000
static constexpr size_t I_FLAG   = 920008;   // 1 (1 = inputs are f32, 0 = packed bf16)

// ---------------- input dtype detection ----------------
__global__ void detect_dtype(const unsigned* __restrict__ x, int* flag) {
    unsigned w = x[threadIdx.x & 63];
    int e = (w >> 23) & 0xFF;
    bool ok = (e > 97) && (e < 157);
    unsigned long long m = __ballot(ok);
    if (threadIdx.x == 0) *flag = (__popcll(m) >= 48) ? 1 : 0;
}

// ---------------- input -> fp32 staging (copy or bf16 expand) ----------------
#define NCONV 25
struct ConvArgs {
    const void* src[NCONV];
    float* dst[NCONV];
    int len[NCONV];
    int boff[NCONV + 1];
};

__global__ __launch_bounds__(256) void convert_all(ConvArgs a, const int* __restrict__ flag) {
    int b = blockIdx.x;
    int ti = 0;
    while (b >= a.boff[ti + 1]) ti++;
    int local = b - a.boff[ti];
    float* d = a.dst[ti];
    int n = a.len[ti];
    int base = local * 1024 + threadIdx.x;
    if (*flag) {
        const float* s = (const float*)a.src[ti];
#pragma unroll
        for (int k = 0; k < 4; k++) {
            int i = base + k * 256;
            if (i < n) d[i] = s[i];
        }
    } else {
        const unsigned short* s = (const unsigned short*)a.src[ti];
#pragma unroll
        for (int k = 0; k < 4; k++) {
            int i = base + k * 256;
            if (i < n) d[i] = __uint_as_float(((unsigned)s[i]) << 16);
        }
    }
}

// ---------------- CSR build ----------------
__global__ __launch_bounds__(256) void count_edges(const int* __restrict__ c1,
                                                   const int* __restrict__ rev_dst,
                                                   int* cnt_dt, int* cnt_od) {
    int i = blockIdx.x * 256 + threadIdx.x;
    if (i < NE1) atomicAdd(&cnt_dt[c1[i]], 1);
    if (i < NE2) atomicAdd(&cnt_od[rev_dst[i]], 1);
}

// Fast single-pass blocked scan: 1024 threads, PER=30 elements/thread (registers),
// wave shfl-scan of thread totals + 16-wave offset scan. 2 barriers total.
#define SCAN_PER 30
__global__ __launch_bounds__(1024) void scan2(const int* __restrict__ cnt_dt, int* rs_dt, int* cur_dt,
                                              const int* __restrict__ cnt_od, int* rs_od, int* cur_od) {
    const int* cnt; int* rs; int* cur; int n;
    if (blockIdx.x == 0) { cnt = cnt_dt; rs = rs_dt; cur = cur_dt; n = NDT; }
    else                 { cnt = cnt_od; rs = rs_od; cur = cur_od; n = NOD; }
    int t = threadIdx.x;
    int lane = t & 63, wave = t >> 6;
    int base = t * SCAN_PER;
    int vals[SCAN_PER];
    int sum = 0;
#pragma unroll
    for (int i = 0; i < SCAN_PER; i++) {
        int idx = base + i;
        int v = (idx < n) ? cnt[idx] : 0;
        vals[i] = sum;        // exclusive-within-thread prefix
        sum += v;
    }
    // inclusive wave scan of per-thread sums
    int x = sum;
#pragma unroll
    for (int off = 1; off < 64; off <<= 1) {
        int y = __shfl_up(x, off, 64);
        if (lane >= off) x += y;
    }
    __shared__ int wsum[16], woff[16];
    if (lane == 63) wsum[wave] = x;
    __syncthreads();
    if (t == 0) {
        int acc = 0;
#pragma unroll
        for (int w = 0; w < 16; w++) { woff[w] = acc; acc += wsum[w]; }
        rs[n] = acc;
    }
    __syncthreads();
    int excl = x - sum + woff[wave];
#pragma unroll
    for (int i = 0; i < SCAN_PER; i++) {
        int idx = base + i;
        if (idx < n) { int e = excl + vals[i]; rs[idx] = e; cur[idx] = e; }
    }
}

__global__ __launch_bounds__(256) void fill_edges(const int* __restrict__ r1, const int* __restrict__ c1,
                                                  const int* __restrict__ rev_src, const int* __restrict__ rev_dst,
                                                  int* cur_dt, int* srcs_dt, int* cur_od, int* srcs_od) {
    int i = blockIdx.x * 256 + threadIdx.x;
    if (i < NE1) { int p = atomicAdd(&cur_dt[c1[i]], 1); srcs_dt[p] = r1[i]; }
    if (i < NE2) { int p = atomicAdd(&cur_od[rev_dst[i]], 1); srcs_od[p] = rev_src[i]; }
}

// ---------------- segment mean (gather, dim=128) ----------------
__global__ __launch_bounds__(128) void seg_mean(const float* __restrict__ X,
                                                const int* __restrict__ rs,
                                                const int* __restrict__ srcs,
                                                float* __restrict__ out) {
    int b = blockIdx.x;
    int t = threadIdx.x;
    int start = rs[b], end = rs[b + 1];
    float a0 = 0.f, a1 = 0.f, a2 = 0.f, a3 = 0.f;
    int j = start;
    for (; j + 3 < end; j += 4) {
        int s0 = srcs[j], s1 = srcs[j + 1], s2 = srcs[j + 2], s3 = srcs[j + 3];
        a0 += X[(size_t)s0 * 128 + t];
        a1 += X[(size_t)s1 * 128 + t];
        a2 += X[(size_t)s2 * 128 + t];
        a3 += X[(size_t)s3 * 128 + t];
    }
    for (; j < end; j++) a0 += X[(size_t)srcs[j] * 128 + t];
    int deg = end - start;
    float s = (a0 + a1) + (a2 + a3);
    out[(size_t)b * 128 + t] = deg > 0 ? s / (float)deg : 0.f;
}

// ---------------- sage layer: out = relu(A1@W1 + A2@W2 + b), N=128 ----------------
__global__ __launch_bounds__(256) void sage_layer(const float* __restrict__ A1, const float* __restrict__ W1,
                                                  const float* __restrict__ A2, const float* __restrict__ W2,
                                                  int K2, const float* __restrict__ bias,
                                                  float* __restrict__ out, int M) {
    __shared__ __align__(16) float As[32 * 132];
    __shared__ __align__(16) float Ws[64 * 128];
    int t = threadIdx.x;
    int tx = t & 31, ty = t >> 5;
    int mb = blockIdx.x * 32;
    float acc[4][4] = {};
    for (int phase = 0; phase < 2; ++phase) {
        const float* A = phase ? A2 : A1;
        const float* Wp = phase ? W2 : W1;
        int K = phase ? K2 : 128;
        int ksh = (K == 128) ? 7 : 6;
        int total = 32 * K;
        for (int idx = t * 4; idx < total; idx += 1024) {
            int row = idx >> ksh, k = idx & (K - 1);
            int m = mb + row; if (m > M - 1) m = M - 1;
            *(float4*)(As + row * 132 + k) = *(const float4*)(A + (size_t)m * K + k);
        }
        for (int kc = 0; kc < K; kc += 64) {
            for (int idx = t * 4; idx < 64 * 128; idx += 1024) {
                int kk = idx >> 7, n = idx & 127;
                *(float4*)(Ws + kk * 128 + n) = *(const float4*)(Wp + (size_t)(kc + kk) * 128 + n);
            }
            __syncthreads();
            for (int k0 = 0; k0 < 64; k0 += 4) {
                float4 av0 = *(const float4*)(As + (ty * 4 + 0) * 132 + kc + k0);
                float4 av1 = *(const float4*)(As + (ty * 4 + 1) * 132 + kc + k0);
                float4 av2 = *(const float4*)(As + (ty * 4 + 2) * 132 + kc + k0);
                float4 av3 = *(const float4*)(As + (ty * 4 + 3) * 132 + kc + k0);
                const float* a0 = (const float*)&av0;
                const float* a1 = (const float*)&av1;
                const float* a2 = (const float*)&av2;
                const float* a3 = (const float*)&av3;
#pragma unroll
                for (int kk = 0; kk < 4; kk++) {
                    float4 wv = *(const float4*)(Ws + (k0 + kk) * 128 + tx * 4);
                    float x0 = a0[kk], x1 = a1[kk], x2 = a2[kk], x3 = a3[kk];
                    acc[0][0] = fmaf(x0, wv.x, acc[0][0]); acc[0][1] = fmaf(x0, wv.y, acc[0][1]);
                    acc[0][2] = fmaf(x0, wv.z, acc[0][2]); acc[0][3] = fmaf(x0, wv.w, acc[0][3]);
                    acc[1][0] = fmaf(x1, wv.x, acc[1][0]); acc[1][1] = fmaf(x1, wv.y, acc[1][1]);
                    acc[1][2] = fmaf(x1, wv.z, acc[1][2]); acc[1][3] = fmaf(x1, wv.w, acc[1][3]);
                    acc[2][0] = fmaf(x2, wv.x, acc[2][0]); acc[2][1] = fmaf(x2, wv.y, acc[2][1]);
                    acc[2][2] = fmaf(x2, wv.z, acc[2][2]); acc[2][3] = fmaf(x2, wv.w, acc[2][3]);
                    acc[3][0] = fmaf(x3, wv.x, acc[3][0]); acc[3][1] = fmaf(x3, wv.y, acc[3][1]);
                    acc[3][2] = fmaf(x3, wv.z, acc[3][2]); acc[3][3] = fmaf(x3, wv.w, acc[3][3]);
                }
            }
            __syncthreads();
        }
    }
    float4 bv = *(const float4*)(bias + tx * 4);
#pragma unroll
    for (int j = 0; j < 4; j++) {
        int m = mb + ty * 4 + j;
        if (m < M) {
            float4 r;
            r.x = fmaxf(acc[j][0] + bv.x, 0.f);
            r.y = fmaxf(acc[j][1] + bv.y, 0.f);
            r.z = fmaxf(acc[j][2] + bv.z, 0.f);
            r.w = fmaxf(acc[j][3] + bv.w, 0.f);
            *(float4*)(out + (size_t)m * 128 + tx * 4) = r;
        }
    }
}

// ---------------- linear: out[M,64] = A[M,128] @ W[128,64] ----------------
__global__ __launch_bounds__(256) void lin_gemm(const float* __restrict__ A, const float* __restrict__ W,
                                                float* __restrict__ out, int M) {
    __shared__ __align__(16) float Ws[128 * 64];
    __shared__ __align__(16) float As[64 * 68];
    int t = threadIdx.x;
    int tx = t & 15, ty = t >> 4;
    int mb = blockIdx.x * 64;
    float acc[4][4] = {};
    for (int idx = t * 4; idx < 128 * 64; idx += 1024)
        *(float4*)(Ws + idx) = *(const float4*)(W + idx);
    for (int kc = 0; kc < 128; kc += 64) {
        __syncthreads();
        for (int idx = t * 4; idx < 64 * 64; idx += 1024) {
            int row = idx >> 6, k = idx & 63;
            int m = mb + row; if (m > M - 1) m = M - 1;
            *(float4*)(As + row * 68 + k) = *(const float4*)(A + (size_t)m * 128 + kc + k);
        }
        __syncthreads();
        for (int k0 = 0; k0 < 64; k0 += 4) {
            float4 av0 = *(const float4*)(As + (ty * 4 + 0) * 68 + k0);
            float4 av1 = *(const float4*)(As + (ty * 4 + 1) * 68 + k0);
            float4 av2 = *(const float4*)(As + (ty * 4 + 2) * 68 + k0);
            float4 av3 = *(const float4*)(As + (ty * 4 + 3) * 68 + k0);
            const float* a0 = (const float*)&av0;
            const float* a1 = (const float*)&av1;
            const float* a2 = (const float*)&av2;
            const float* a3 = (const float*)&av3;
#pragma unroll
            for (int kk = 0; kk < 4; kk++) {
                float4 wv = *(const float4*)(Ws + (kc + k0 + kk) * 64 + tx * 4);
                float x0 = a0[kk], x1 = a1[kk], x2 = a2[kk], x3 = a3[kk];
                acc[0][0] = fmaf(x0, wv.x, acc[0][0]); acc[0][1] = fmaf(x0, wv.y, acc[0][1]);
                acc[0][2] = fmaf(x0, wv.z, acc[0][2]); acc[0][3] = fmaf(x0, wv.w, acc[0][3]);
                acc[1][0] = fmaf(x1, wv.x, acc[1][0]); acc[1][1] = fmaf(x1, wv.y, acc[1][1]);
                acc[1][2] = fmaf(x1, wv.z, acc[1][2]); acc[1][3] = fmaf(x1, wv.w, acc[1][3]);
                acc[2][0] = fmaf(x2, wv.x, acc[2][0]); acc[2][1] = fmaf(x2, wv.y, acc[2][1]);
                acc[2][2] = fmaf(x2, wv.z, acc[2][2]); acc[2][3] = fmaf(x2, wv.w, acc[2][3]);
                acc[3][0] = fmaf(x3, wv.x, acc[3][0]); acc[3][1] = fmaf(x3, wv.y, acc[3][1]);
                acc[3][2] = fmaf(x3, wv.z, acc[3][2]); acc[3][3] = fmaf(x3, wv.w, acc[3][3]);
            }
        }
    }
#pragma unroll
    for (int j = 0; j < 4; j++) {
        int m = mb + ty * 4 + j;
        if (m < M) {
            float4 r = { acc[j][0], acc[j][1], acc[j][2], acc[j][3] };
            *(float4*)(out + (size_t)m * 64 + tx * 4) = r;
        }
    }
}

// ---------------- decoder weight fusion ----------------
__global__ __launch_bounds__(256) void fuse_dec(const float* __restrict__ od_lw, const float* __restrict__ od_lb,
                                                const float* __restrict__ dt_lw, const float* __restrict__ dt_lb,
                                                const float* __restrict__ w1, const float* __restrict__ b1,
                                                float* Wod, float* Wdt, float* bfuse) {
    int i = blockIdx.x * 256 + threadIdx.x;
    if (i < 8192) {
        int r = i >> 6, p = i & 63;
        float s = 0.f;
        for (int j = 0; j < 64; j++) s = fmaf(od_lw[r * 64 + j], w1[j * 64 + p], s);
        Wod[i] = s;
    } else if (i < 16384) {
        int q = i - 8192, r = q >> 6, p = q & 63;
        float s = 0.f;
        for (int j = 0; j < 64; j++) s = fmaf(dt_lw[r * 64 + j], w1[(64 + j) * 64 + p], s);
        Wdt[q] = s;
    } else if (i < 16448) {
        int p = i - 16384;
        float s = b1[p];
        for (int j = 0; j < 64; j++) {
            s = fmaf(od_lb[j], w1[j * 64 + p], s);
            s = fmaf(dt_lb[j], w1[(64 + j) * 64 + p], s);
        }
        bfuse[p] = s;
    }
}

// ---------------- decoder (FLOAT32 output) ----------------
__global__ __launch_bounds__(256) void decode(const float* __restrict__ P_od, const float* __restrict__ P_dt,
                                              const int* __restrict__ el_src, const int* __restrict__ el_dst,
                                              const float* __restrict__ bfuse, const float* __restrict__ w2,
                                              const float* __restrict__ b2v, float* __restrict__ out) {
    __shared__ __align__(16) float bf[64];
    __shared__ __align__(16) float w2s[64];
    int t = threadIdx.x;
    if (t < 64) { bf[t] = bfuse[t]; w2s[t] = w2[t]; }
    __syncthreads();
    int e = blockIdx.x * 256 + t;
    if (e >= NEL) return;
    const float4* po = (const float4*)(P_od + (size_t)el_src[e] * 64);
    const float4* pt = (const float4*)(P_dt + (size_t)el_dst[e] * 64);
    float acc = 0.f;
#pragma unroll 4
    for (int c = 0; c < 16; c++) {
        float4 a = po[c], b = pt[c];
        float4 bb = *(const float4*)&bf[c * 4];
        float4 ww = *(const float4*)&w2s[c * 4];
        acc = fmaf(fmaxf(a.x + b.x + bb.x, 0.f), ww.x, acc);
        acc = fmaf(fmaxf(a.y + b.y + bb.y, 0.f), ww.y, acc);
        acc = fmaf(fmaxf(a.z + b.z + bb.z, 0.f), ww.z, acc);
        acc = fmaf(fmaxf(a.w + b.w + bb.w, 0.f), ww.w, acc);
    }
    float z = acc + b2v[0];
    out[e] = 1.f / (1.f + __expf(-z));
}

// ---------------- launch ----------------
extern "C" void kernel_launch(void* const* d_in, const int* in_sizes, int n_in,
                              void* d_out, int out_size, void* d_ws, size_t ws_size,
                              hipStream_t stream) {
    float* W = (float*)d_ws;
    int* I = (int*)(W + F_END);

    const int* ei = (const int*)d_in[2];
    const int* r1 = ei;
    const int* c1 = ei + NE1;
    const int* rev_src = (const int*)d_in[3];
    const int* rev_dst = (const int*)d_in[4];
    const int* el_src = (const int*)d_in[5];
    const int* el_dst = (const int*)d_in[6];

    // zero edge counters (cnt_dt + cnt_od adjacent)
    hipMemsetAsync(I + I_CNT_DT, 0, (NDT + NOD) * sizeof(int), stream);

    // detect whether float inputs are f32-stored or packed bf16
    detect_dtype<<<1, 64, 0, stream>>>((const unsigned*)d_in[0], I + I_FLAG);

    // stage all float tensors into fp32 workspace
    ConvArgs ca;
    const int iidx[NCONV] = {0,1, 7,8,9, 10,11,12, 13,14,15, 16,17, 18,19,20, 21,22,23, 24,25, 26,27,28,29};
    const size_t foff[NCONV] = {F_XDT, F_XOD, F_OD1_WL, F_OD1_WR, F_OD1_B, F_OD2_WL, F_OD2_WR, F_OD2_B,
                                F_OD3_WL, F_OD3_WR, F_OD3_B, F_OD_LW, F_OD_LB, F_DT1_WL, F_DT1_WR, F_DT1_B,
                                F_DT2_WL, F_DT2_WR, F_DT2_B, F_DT_LW, F_DT_LB, F_DEC_W1, F_DEC_B1, F_DEC_W2, F_DEC_B2};
    const int lens[NCONV] = {NDT * 128, NOD * 64, 16384, 16384, 128, 16384, 8192, 128,
                             16384, 16384, 128, 8192, 64, 16384, 16384, 128,
                             16384, 16384, 128, 8192, 64, 8192, 64, 64, 1};
    int btot = 0;
    for (int i = 0; i < NCONV; i++) {
        ca.src[i] = d_in[iidx[i]];
        ca.dst[i] = W + foff[i];
        ca.len[i] = lens[i];
        ca.boff[i] = btot;
        btot += (lens[i] + 1023) / 1024;
    }
    ca.boff[NCONV] = btot;
    convert_all<<<btot, 256, 0, stream>>>(ca, I + I_FLAG);

    // CSR build for both graphs
    count_edges<<<(NE1 + 255) / 256, 256, 0, stream>>>(c1, rev_dst, I + I_CNT_DT, I + I_CNT_OD);
    scan2<<<2, 1024, 0, stream>>>(I + I_CNT_DT, I + I_RS_DT, I + I_CUR_DT,
                                  I + I_CNT_OD, I + I_RS_OD, I + I_CUR_OD);
    fill_edges<<<(NE1 + 255) / 256, 256, 0, stream>>>(r1, c1, rev_src, rev_dst,
                                                      I + I_CUR_DT, I + I_SRC_DT,
                                                      I + I_CUR_OD, I + I_SRC_OD);

    // decoder weight fusion (independent)
    fuse_dec<<<(16448 + 255) / 256, 256, 0, stream>>>(W + F_OD_LW, W + F_OD_LB, W + F_DT_LW, W + F_DT_LB,
                                                      W + F_DEC_W1, W + F_DEC_B1,
                                                      W + F_WOD, W + F_WDT, W + F_BFUSE);

    // agg_x = segmean(x_dt) over ei_dt  -> BUFA
    seg_mean<<<NDT, 128, 0, stream>>>(W + F_XDT, I + I_RS_DT, I + I_SRC_DT, W + F_BUFA);
    // h  = relu(agg_x@od1_wl + x_dt@od1_wr + b) -> BUFH
    sage_layer<<<(NDT + 31) / 32, 256, 0, stream>>>(W + F_BUFA, W + F_OD1_WL, W + F_XDT, W + F_OD1_WR, 128,
                                                    W + F_OD1_B, W + F_BUFH, NDT);
    // d1 = relu(agg_x@dt1_wl + x_dt@dt1_wr + b) -> BUFD
    sage_layer<<<(NDT + 31) / 32, 256, 0, stream>>>(W + F_BUFA, W + F_DT1_WL, W + F_XDT, W + F_DT1_WR, 128,
                                                    W + F_DT1_B, W + F_BUFD, NDT);
    // agg_h = segmean(h) over ei_rev -> AGGH
    seg_mean<<<NOD, 128, 0, stream>>>(W + F_BUFH, I + I_RS_OD, I + I_SRC_OD, W + F_AGGH);
    // od2 = relu(agg_h@od2_wl + x_od@od2_wr + b)
    sage_layer<<<(NOD + 31) / 32, 256, 0, stream>>>(W + F_AGGH, W + F_OD2_WL, W + F_XOD, W + F_OD2_WR, 64,
                                                    W + F_OD2_B, W + F_OD2, NOD);
    // od3 = relu(agg_h@od3_wl + od2@od3_wr + b)
    sage_layer<<<(NOD + 31) / 32, 256, 0, stream>>>(W + F_AGGH, W + F_OD3_WL, W + F_OD2, W + F_OD3_WR, 128,
                                                    W + F_OD3_B, W + F_OD3, NOD);
    // agg_d = segmean(d1) over ei_dt -> BUFA (agg_x dead)
    seg_mean<<<NDT, 128, 0, stream>>>(W + F_BUFD, I + I_RS_DT, I + I_SRC_DT, W + F_BUFA);
    // d2 = relu(agg_d@dt2_wl + d1@dt2_wr + b) -> BUFH (h dead)
    sage_layer<<<(NDT + 31) / 32, 256, 0, stream>>>(W + F_BUFA, W + F_DT2_WL, W + F_BUFD, W + F_DT2_WR, 128,
                                                    W + F_DT2_B, W + F_BUFH, NDT);
    // P_od = od3 @ Wod ; P_dt = d2 @ Wdt
    lin_gemm<<<(NOD + 63) / 64, 256, 0, stream>>>(W + F_OD3, W + F_WOD, W + F_POD, NOD);
    lin_gemm<<<(NDT + 63) / 64, 256, 0, stream>>>(W + F_BUFH, W + F_WDT, W + F_PDT, NDT);
    // decoder
    decode<<<(NEL + 255) / 256, 256, 0, stream>>>(W + F_POD, W + F_PDT, el_src, el_dst,
                                                  W + F_BFUSE, W + F_DEC_W2, W + F_DEC_B2,
                                                  (float*)d_out);
}

// Round 5
// 510.134 us; speedup vs baseline: 1.1066x; 1.0510x over previous
//
#include <hip/hip_runtime.h>
#include <hip/hip_bf16.h>

#define NDT 30000
#define NOD 10000
#define NE1 500000
#define NE2 300000
#define NEL 200000

// ---------------- workspace layout (float units) ----------------
static constexpr size_t F_WOD   = 0;                               // 8192
static constexpr size_t F_WDT   = F_WOD + 8192;                    // 8192
static constexpr size_t F_BFUSE = F_WDT + 8192;                    // 64
static constexpr size_t F_BUFA  = F_BFUSE + 64;                    // NDT*128 (agg_x, later agg_d)
static constexpr size_t F_BUFH  = F_BUFA + (size_t)NDT * 128;      // h, later d2
static constexpr size_t F_BUFD  = F_BUFH + (size_t)NDT * 128;      // d1
static constexpr size_t F_AGGH  = F_BUFD + (size_t)NDT * 128;      // NOD*128
static constexpr size_t F_OD2   = F_AGGH + (size_t)NOD * 128;
static constexpr size_t F_OD3   = F_OD2 + (size_t)NOD * 128;
static constexpr size_t F_POD   = F_OD3 + (size_t)NOD * 128;       // NOD*64
static constexpr size_t F_PDT   = F_POD + (size_t)NOD * 64;        // NDT*64
static constexpr size_t F_END   = F_PDT + (size_t)NDT * 64;
// int region (indices into int* base = (int*)(ws + F_END))
static constexpr size_t I_CNT_DT = 0;        // 30000
static constexpr size_t I_CNT_OD = 30000;    // 10000  (adjacent -> one memset)
static constexpr size_t I_RS_DT  = 40000;    // 30001 (+pad)
static constexpr size_t I_RS_OD  = 70004;    // 10001 (+pad)
static constexpr size_t I_CUR_DT = 80008;    // 30000
static constexpr size_t I_CUR_OD = 110008;   // 10000
static constexpr size_t I_SRC_DT = 120008;   // 500000
static constexpr size_t I_SRC_OD = 620008;   // 300000

// ---------------- CSR build ----------------
// ILP-4: each thread owns 4 consecutive edges of each graph -> 4-8 independent
// atomic chains in flight (latency-bound kernel, VALUBusy ~0.5%).
__global__ __launch_bounds__(256) void count_edges(const int* __restrict__ c1,
                                                   const int* __restrict__ rev_dst,
                                                   int* cnt_dt, int* cnt_od) {
    int b = (blockIdx.x * 256 + threadIdx.x) * 4;
    if (b + 3 < NE1) {
        int4 v = *(const int4*)(c1 + b);
        atomicAdd(&cnt_dt[v.x], 1); atomicAdd(&cnt_dt[v.y], 1);
        atomicAdd(&cnt_dt[v.z], 1); atomicAdd(&cnt_dt[v.w], 1);
    } else {
        for (int i = b; i < NE1; i++) atomicAdd(&cnt_dt[c1[i]], 1);
    }
    if (b + 3 < NE2) {
        int4 v = *(const int4*)(rev_dst + b);
        atomicAdd(&cnt_od[v.x], 1); atomicAdd(&cnt_od[v.y], 1);
        atomicAdd(&cnt_od[v.z], 1); atomicAdd(&cnt_od[v.w], 1);
    } else if (b < NE2) {
        for (int i = b; i < NE2; i++) atomicAdd(&cnt_od[rev_dst[i]], 1);
    }
}

// single-pass blocked scan, 2 barriers
#define SCAN_PER 30
__global__ __launch_bounds__(1024) void scan2(const int* __restrict__ cnt_dt, int* rs_dt, int* cur_dt,
                                              const int* __restrict__ cnt_od, int* rs_od, int* cur_od) {
    const int* cnt; int* rs; int* cur; int n;
    if (blockIdx.x == 0) { cnt = cnt_dt; rs = rs_dt; cur = cur_dt; n = NDT; }
    else                 { cnt = cnt_od; rs = rs_od; cur = cur_od; n = NOD; }
    int t = threadIdx.x;
    int lane = t & 63, wave = t >> 6;
    int base = t * SCAN_PER;
    int vals[SCAN_PER];
    int sum = 0;
#pragma unroll
    for (int i = 0; i < SCAN_PER; i++) {
        int idx = base + i;
        int v = (idx < n) ? cnt[idx] : 0;
        vals[i] = sum;
        sum += v;
    }
    int x = sum;
#pragma unroll
    for (int off = 1; off < 64; off <<= 1) {
        int y = __shfl_up(x, off, 64);
        if (lane >= off) x += y;
    }
    __shared__ int wsum[16], woff[16];
    if (lane == 63) wsum[wave] = x;
    __syncthreads();
    if (t == 0) {
        int acc = 0;
#pragma unroll
        for (int w = 0; w < 16; w++) { woff[w] = acc; acc += wsum[w]; }
        rs[n] = acc;
    }
    __syncthreads();
    int excl = x - sum + woff[wave];
#pragma unroll
    for (int i = 0; i < SCAN_PER; i++) {
        int idx = base + i;
        if (idx < n) { int e = excl + vals[i]; rs[idx] = e; cur[idx] = e; }
    }
}

__global__ __launch_bounds__(256) void fill_edges(const int* __restrict__ r1, const int* __restrict__ c1,
                                                  const int* __restrict__ rev_src, const int* __restrict__ rev_dst,
                                                  int* cur_dt, int* srcs_dt, int* cur_od, int* srcs_od) {
    int b = (blockIdx.x * 256 + threadIdx.x) * 4;
    if (b + 3 < NE1) {
        int4 d = *(const int4*)(c1 + b);
        int4 s = *(const int4*)(r1 + b);
        int p0 = atomicAdd(&cur_dt[d.x], 1);
        int p1 = atomicAdd(&cur_dt[d.y], 1);
        int p2 = atomicAdd(&cur_dt[d.z], 1);
        int p3 = atomicAdd(&cur_dt[d.w], 1);
        srcs_dt[p0] = s.x; srcs_dt[p1] = s.y; srcs_dt[p2] = s.z; srcs_dt[p3] = s.w;
    } else {
        for (int i = b; i < NE1; i++) { int p = atomicAdd(&cur_dt[c1[i]], 1); srcs_dt[p] = r1[i]; }
    }
    if (b + 3 < NE2) {
        int4 d = *(const int4*)(rev_dst + b);
        int4 s = *(const int4*)(rev_src + b);
        int p0 = atomicAdd(&cur_od[d.x], 1);
        int p1 = atomicAdd(&cur_od[d.y], 1);
        int p2 = atomicAdd(&cur_od[d.z], 1);
        int p3 = atomicAdd(&cur_od[d.w], 1);
        srcs_od[p0] = s.x; srcs_od[p1] = s.y; srcs_od[p2] = s.z; srcs_od[p3] = s.w;
    } else if (b < NE2) {
        for (int i = b; i < NE2; i++) { int p = atomicAdd(&cur_od[rev_dst[i]], 1); srcs_od[p] = rev_src[i]; }
    }
}

// ---------------- segment mean (gather, dim=128) ----------------
__global__ __launch_bounds__(128) void seg_mean(const float* __restrict__ X,
                                                const int* __restrict__ rs,
                                                const int* __restrict__ srcs,
                                                float* __restrict__ out) {
    int b = blockIdx.x;
    int t = threadIdx.x;
    int start = rs[b], end = rs[b + 1];
    float a0 = 0.f, a1 = 0.f, a2 = 0.f, a3 = 0.f;
    int j = start;
    for (; j + 3 < end; j += 4) {
        int s0 = srcs[j], s1 = srcs[j + 1], s2 = srcs[j + 2], s3 = srcs[j + 3];
        a0 += X[(size_t)s0 * 128 + t];
        a1 += X[(size_t)s1 * 128 + t];
        a2 += X[(size_t)s2 * 128 + t];
        a3 += X[(size_t)s3 * 128 + t];
    }
    for (; j < end; j++) a0 += X[(size_t)srcs[j] * 128 + t];
    int deg = end - start;
    float s = (a0 + a1) + (a2 + a3);
    out[(size_t)b * 128 + t] = deg > 0 ? s / (float)deg : 0.f;
}

// ---------------- dual sage layer: shares A-operands between two weight sets ----
// outa = relu(A1@Wa1 + A2@Wa2 + ba) ; outb = relu(A1@Wb1 + A2@Wb2 + bb); K=128 both.
__global__ __launch_bounds__(256) void sage_dual(const float* __restrict__ A1,
                                                 const float* __restrict__ Wa1, const float* __restrict__ Wb1,
                                                 const float* __restrict__ A2,
                                                 const float* __restrict__ Wa2, const float* __restrict__ Wb2,
                                                 const float* __restrict__ ba, const float* __restrict__ bb,
                                                 float* __restrict__ outa, float* __restrict__ outb, int M) {
    __shared__ __align__(16) float As[32 * 132];
    __shared__ __align__(16) float Wsa[32 * 128];
    __shared__ __align__(16) float Wsb[32 * 128];
    int t = threadIdx.x;
    int tx = t & 31, ty = t >> 5;
    int mb = blockIdx.x * 32;
    float acca[4][4] = {}, accb[4][4] = {};
    for (int phase = 0; phase < 2; ++phase) {
        const float* A  = phase ? A2 : A1;
        const float* Wa = phase ? Wa2 : Wa1;
        const float* Wb = phase ? Wb2 : Wb1;
        for (int idx = t * 4; idx < 4096; idx += 1024) {
            int row = idx >> 7, k = idx & 127;
            int m = mb + row; if (m > M - 1) m = M - 1;
            *(float4*)(As + row * 132 + k) = *(const float4*)(A + (size_t)m * 128 + k);
        }
        for (int kc = 0; kc < 128; kc += 32) {
            for (int idx = t * 4; idx < 4096; idx += 1024) {
                int r = idx >> 7, n = idx & 127;
                *(float4*)(Wsa + r * 128 + n) = *(const float4*)(Wa + (size_t)(kc + r) * 128 + n);
                *(float4*)(Wsb + r * 128 + n) = *(const float4*)(Wb + (size_t)(kc + r) * 128 + n);
            }
            __syncthreads();
            for (int k0 = 0; k0 < 32; k0 += 4) {
                float4 av0 = *(const float4*)(As + (ty * 4 + 0) * 132 + kc + k0);
                float4 av1 = *(const float4*)(As + (ty * 4 + 1) * 132 + kc + k0);
                float4 av2 = *(const float4*)(As + (ty * 4 + 2) * 132 + kc + k0);
                float4 av3 = *(const float4*)(As + (ty * 4 + 3) * 132 + kc + k0);
                const float* a0 = (const float*)&av0;
                const float* a1 = (const float*)&av1;
                const float* a2 = (const float*)&av2;
                const float* a3 = (const float*)&av3;
#pragma unroll
                for (int kk = 0; kk < 4; kk++) {
                    float4 wa = *(const float4*)(Wsa + (k0 + kk) * 128 + tx * 4);
                    float4 wb = *(const float4*)(Wsb + (k0 + kk) * 128 + tx * 4);
                    float x0 = a0[kk], x1 = a1[kk], x2 = a2[kk], x3 = a3[kk];
                    acca[0][0] = fmaf(x0, wa.x, acca[0][0]); acca[0][1] = fmaf(x0, wa.y, acca[0][1]);
                    acca[0][2] = fmaf(x0, wa.z, acca[0][2]); acca[0][3] = fmaf(x0, wa.w, acca[0][3]);
                    acca[1][0] = fmaf(x1, wa.x, acca[1][0]); acca[1][1] = fmaf(x1, wa.y, acca[1][1]);
                    acca[1][2] = fmaf(x1, wa.z, acca[1][2]); acca[1][3] = fmaf(x1, wa.w, acca[1][3]);
                    acca[2][0] = fmaf(x2, wa.x, acca[2][0]); acca[2][1] = fmaf(x2, wa.y, acca[2][1]);
                    acca[2][2] = fmaf(x2, wa.z, acca[2][2]); acca[2][3] = fmaf(x2, wa.w, acca[2][3]);
                    acca[3][0] = fmaf(x3, wa.x, acca[3][0]); acca[3][1] = fmaf(x3, wa.y, acca[3][1]);
                    acca[3][2] = fmaf(x3, wa.z, acca[3][2]); acca[3][3] = fmaf(x3, wa.w, acca[3][3]);
                    accb[0][0] = fmaf(x0, wb.x, accb[0][0]); accb[0][1] = fmaf(x0, wb.y, accb[0][1]);
                    accb[0][2] = fmaf(x0, wb.z, accb[0][2]); accb[0][3] = fmaf(x0, wb.w, accb[0][3]);
                    accb[1][0] = fmaf(x1, wb.x, accb[1][0]); accb[1][1] = fmaf(x1, wb.y, accb[1][1]);
                    accb[1][2] = fmaf(x1, wb.z, accb[1][2]); accb[1][3] = fmaf(x1, wb.w, accb[1][3]);
                    accb[2][0] = fmaf(x2, wb.x, accb[2][0]); accb[2][1] = fmaf(x2, wb.y, accb[2][1]);
                    accb[2][2] = fmaf(x2, wb.z, accb[2][2]); accb[2][3] = fmaf(x2, wb.w, accb[2][3]);
                    accb[3][0] = fmaf(x3, wb.x, accb[3][0]); accb[3][1] = fmaf(x3, wb.y, accb[3][1]);
                    accb[3][2] = fmaf(x3, wb.z, accb[3][2]); accb[3][3] = fmaf(x3, wb.w, accb[3][3]);
                }
            }
            __syncthreads();
        }
    }
    float4 bva = *(const float4*)(ba + tx * 4);
    float4 bvb = *(const float4*)(bb + tx * 4);
#pragma unroll
    for (int j = 0; j < 4; j++) {
        int m = mb + ty * 4 + j;
        if (m < M) {
            float4 ra, rb;
            ra.x = fmaxf(acca[j][0] + bva.x, 0.f); ra.y = fmaxf(acca[j][1] + bva.y, 0.f);
            ra.z = fmaxf(acca[j][2] + bva.z, 0.f); ra.w = fmaxf(acca[j][3] + bva.w, 0.f);
            rb.x = fmaxf(accb[j][0] + bvb.x, 0.f); rb.y = fmaxf(accb[j][1] + bvb.y, 0.f);
            rb.z = fmaxf(accb[j][2] + bvb.z, 0.f); rb.w = fmaxf(accb[j][3] + bvb.w, 0.f);
            *(float4*)(outa + (size_t)m * 128 + tx * 4) = ra;
            *(float4*)(outb + (size_t)m * 128 + tx * 4) = rb;
        }
    }
}

// ---------------- sage layer: out = relu(A1@W1 + A2@W2 + b), N=128 ----------------
__global__ __launch_bounds__(256) void sage_layer(const float* __restrict__ A1, const float* __restrict__ W1,
                                                  const float* __restrict__ A2, const float* __restrict__ W2,
                                                  int K2, const float* __restrict__ bias,
                                                  float* __restrict__ out, int M) {
    __shared__ __align__(16) float As[32 * 132];
    __shared__ __align__(16) float Ws[64 * 128];
    int t = threadIdx.x;
    int tx = t & 31, ty = t >> 5;
    int mb = blockIdx.x * 32;
    float acc[4][4] = {};
    for (int phase = 0; phase < 2; ++phase) {
        const float* A = phase ? A2 : A1;
        const float* Wp = phase ? W2 : W1;
        int K = phase ? K2 : 128;
        int ksh = (K == 128) ? 7 : 6;
        int total = 32 * K;
        for (int idx = t * 4; idx < total; idx += 1024) {
            int row = idx >> ksh, k = idx & (K - 1);
            int m = mb + row; if (m > M - 1) m = M - 1;
            *(float4*)(As + row * 132 + k) = *(const float4*)(A + (size_t)m * K + k);
        }
        for (int kc = 0; kc < K; kc += 64) {
            for (int idx = t * 4; idx < 64 * 128; idx += 1024) {
                int kk = idx >> 7, n = idx & 127;
                *(float4*)(Ws + kk * 128 + n) = *(const float4*)(Wp + (size_t)(kc + kk) * 128 + n);
            }
            __syncthreads();
            for (int k0 = 0; k0 < 64; k0 += 4) {
                float4 av0 = *(const float4*)(As + (ty * 4 + 0) * 132 + kc + k0);
                float4 av1 = *(const float4*)(As + (ty * 4 + 1) * 132 + kc + k0);
                float4 av2 = *(const float4*)(As + (ty * 4 + 2) * 132 + kc + k0);
                float4 av3 = *(const float4*)(As + (ty * 4 + 3) * 132 + kc + k0);
                const float* a0 = (const float*)&av0;
                const float* a1 = (const float*)&av1;
                const float* a2 = (const float*)&av2;
                const float* a3 = (const float*)&av3;
#pragma unroll
                for (int kk = 0; kk < 4; kk++) {
                    float4 wv = *(const float4*)(Ws + (k0 + kk) * 128 + tx * 4);
                    float x0 = a0[kk], x1 = a1[kk], x2 = a2[kk], x3 = a3[kk];
                    acc[0][0] = fmaf(x0, wv.x, acc[0][0]); acc[0][1] = fmaf(x0, wv.y, acc[0][1]);
                    acc[0][2] = fmaf(x0, wv.z, acc[0][2]); acc[0][3] = fmaf(x0, wv.w, acc[0][3]);
                    acc[1][0] = fmaf(x1, wv.x, acc[1][0]); acc[1][1] = fmaf(x1, wv.y, acc[1][1]);
                    acc[1][2] = fmaf(x1, wv.z, acc[1][2]); acc[1][3] = fmaf(x1, wv.w, acc[1][3]);
                    acc[2][0] = fmaf(x2, wv.x, acc[2][0]); acc[2][1] = fmaf(x2, wv.y, acc[2][1]);
                    acc[2][2] = fmaf(x2, wv.z, acc[2][2]); acc[2][3] = fmaf(x2, wv.w, acc[2][3]);
                    acc[3][0] = fmaf(x3, wv.x, acc[3][0]); acc[3][1] = fmaf(x3, wv.y, acc[3][1]);
                    acc[3][2] = fmaf(x3, wv.z, acc[3][2]); acc[3][3] = fmaf(x3, wv.w, acc[3][3]);
                }
            }
            __syncthreads();
        }
    }
    float4 bv = *(const float4*)(bias + tx * 4);
#pragma unroll
    for (int j = 0; j < 4; j++) {
        int m = mb + ty * 4 + j;
        if (m < M) {
            float4 r;
            r.x = fmaxf(acc[j][0] + bv.x, 0.f);
            r.y = fmaxf(acc[j][1] + bv.y, 0.f);
            r.z = fmaxf(acc[j][2] + bv.z, 0.f);
            r.w = fmaxf(acc[j][3] + bv.w, 0.f);
            *(float4*)(out + (size_t)m * 128 + tx * 4) = r;
        }
    }
}

// ---------------- linear: out[M,64] = A[M,128] @ W[128,64] ----------------
__global__ __launch_bounds__(256) void lin_gemm(const float* __restrict__ A, const float* __restrict__ W,
                                                float* __restrict__ out, int M) {
    __shared__ __align__(16) float Ws[128 * 64];
    __shared__ __align__(16) float As[64 * 68];
    int t = threadIdx.x;
    int tx = t & 15, ty = t >> 4;
    int mb = blockIdx.x * 64;
    float acc[4][4] = {};
    for (int idx = t * 4; idx < 128 * 64; idx += 1024)
        *(float4*)(Ws + idx) = *(const float4*)(W + idx);
    for (int kc = 0; kc < 128; kc += 64) {
        __syncthreads();
        for (int idx = t * 4; idx < 64 * 64; idx += 1024) {
            int row = idx >> 6, k = idx & 63;
            int m = mb + row; if (m > M - 1) m = M - 1;
            *(float4*)(As + row * 68 + k) = *(const float4*)(A + (size_t)m * 128 + kc + k);
        }
        __syncthreads();
        for (int k0 = 0; k0 < 64; k0 += 4) {
            float4 av0 = *(const float4*)(As + (ty * 4 + 0) * 68 + k0);
            float4 av1 = *(const float4*)(As + (ty * 4 + 1) * 68 + k0);
            float4 av2 = *(const float4*)(As + (ty * 4 + 2) * 68 + k0);
            float4 av3 = *(const float4*)(As + (ty * 4 + 3) * 68 + k0);
            const float* a0 = (const float*)&av0;
            const float* a1 = (const float*)&av1;
            const float* a2 = (const float*)&av2;
            const float* a3 = (const float*)&av3;
#pragma unroll
            for (int kk = 0; kk < 4; kk++) {
                float4 wv = *(const float4*)(Ws + (kc + k0 + kk) * 64 + tx * 4);
                float x0 = a0[kk], x1 = a1[kk], x2 = a2[kk], x3 = a3[kk];
                acc[0][0] = fmaf(x0, wv.x, acc[0][0]); acc[0][1] = fmaf(x0, wv.y, acc[0][1]);
                acc[0][2] = fmaf(x0, wv.z, acc[0][2]); acc[0][3] = fmaf(x0, wv.w, acc[0][3]);
                acc[1][0] = fmaf(x1, wv.x, acc[1][0]); acc[1][1] = fmaf(x1, wv.y, acc[1][1]);
                acc[1][2] = fmaf(x1, wv.z, acc[1][2]); acc[1][3] = fmaf(x1, wv.w, acc[1][3]);
                acc[2][0] = fmaf(x2, wv.x, acc[2][0]); acc[2][1] = fmaf(x2, wv.y, acc[2][1]);
                acc[2][2] = fmaf(x2, wv.z, acc[2][2]); acc[2][3] = fmaf(x2, wv.w, acc[2][3]);
                acc[3][0] = fmaf(x3, wv.x, acc[3][0]); acc[3][1] = fmaf(x3, wv.y, acc[3][1]);
                acc[3][2] = fmaf(x3, wv.z, acc[3][2]); acc[3][3] = fmaf(x3, wv.w, acc[3][3]);
            }
        }
    }
#pragma unroll
    for (int j = 0; j < 4; j++) {
        int m = mb + ty * 4 + j;
        if (m < M) {
            float4 r = { acc[j][0], acc[j][1], acc[j][2], acc[j][3] };
            *(float4*)(out + (size_t)m * 64 + tx * 4) = r;
        }
    }
}

// ---------------- decoder weight fusion ----------------
__global__ __launch_bounds__(256) void fuse_dec(const float* __restrict__ od_lw, const float* __restrict__ od_lb,
                                                const float* __restrict__ dt_lw, const float* __restrict__ dt_lb,
                                                const float* __restrict__ w1, const float* __restrict__ b1,
                                                float* Wod, float* Wdt, float* bfuse) {
    int i = blockIdx.x * 256 + threadIdx.x;
    if (i < 8192) {
        int r = i >> 6, p = i & 63;
        float s = 0.f;
        for (int j = 0; j < 64; j++) s = fmaf(od_lw[r * 64 + j], w1[j * 64 + p], s);
        Wod[i] = s;
    } else if (i < 16384) {
        int q = i - 8192, r = q >> 6, p = q & 63;
        float s = 0.f;
        for (int j = 0; j < 64; j++) s = fmaf(dt_lw[r * 64 + j], w1[(64 + j) * 64 + p], s);
        Wdt[q] = s;
    } else if (i < 16448) {
        int p = i - 16384;
        float s = b1[p];
        for (int j = 0; j < 64; j++) {
            s = fmaf(od_lb[j], w1[j * 64 + p], s);
            s = fmaf(dt_lb[j], w1[(64 + j) * 64 + p], s);
        }
        bfuse[p] = s;
    }
}

// ---------------- decoder (f32 output) ----------------
__global__ __launch_bounds__(256) void decode(const float* __restrict__ P_od, const float* __restrict__ P_dt,
                                              const int* __restrict__ el_src, const int* __restrict__ el_dst,
                                              const float* __restrict__ bfuse, const float* __restrict__ w2,
                                              const float* __restrict__ b2v, float* __restrict__ out) {
    __shared__ __align__(16) float bf[64];
    __shared__ __align__(16) float w2s[64];
    int t = threadIdx.x;
    if (t < 64) { bf[t] = bfuse[t]; w2s[t] = w2[t]; }
    __syncthreads();
    int e = blockIdx.x * 256 + t;
    if (e >= NEL) return;
    const float4* po = (const float4*)(P_od + (size_t)el_src[e] * 64);
    const float4* pt = (const float4*)(P_dt + (size_t)el_dst[e] * 64);
    float acc = 0.f;
#pragma unroll 4
    for (int c = 0; c < 16; c++) {
        float4 a = po[c], b = pt[c];
        float4 bb = *(const float4*)&bf[c * 4];
        float4 ww = *(const float4*)&w2s[c * 4];
        acc = fmaf(fmaxf(a.x + b.x + bb.x, 0.f), ww.x, acc);
        acc = fmaf(fmaxf(a.y + b.y + bb.y, 0.f), ww.y, acc);
        acc = fmaf(fmaxf(a.z + b.z + bb.z, 0.f), ww.z, acc);
        acc = fmaf(fmaxf(a.w + b.w + bb.w, 0.f), ww.w, acc);
    }
    float z = acc + b2v[0];
    out[e] = 1.f / (1.f + __expf(-z));
}

// ---------------- launch ----------------
extern "C" void kernel_launch(void* const* d_in, const int* in_sizes, int n_in,
                              void* d_out, int out_size, void* d_ws, size_t ws_size,
                              hipStream_t stream) {
    float* W = (float*)d_ws;
    int* I = (int*)(W + F_END);

    // inputs (f32-stored; verified round 3)
    const float* x_dt   = (const float*)d_in[0];
    const float* x_od   = (const float*)d_in[1];
    const int* ei       = (const int*)d_in[2];
    const int* r1 = ei;
    const int* c1 = ei + NE1;
    const int* rev_src  = (const int*)d_in[3];
    const int* rev_dst  = (const int*)d_in[4];
    const int* el_src   = (const int*)d_in[5];
    const int* el_dst   = (const int*)d_in[6];
    const float* od1_wl = (const float*)d_in[7],  *od1_wr = (const float*)d_in[8],  *od1_b = (const float*)d_in[9];
    const float* od2_wl = (const float*)d_in[10], *od2_wr = (const float*)d_in[11], *od2_b = (const float*)d_in[12];
    const float* od3_wl = (const float*)d_in[13], *od3_wr = (const float*)d_in[14], *od3_b = (const float*)d_in[15];
    const float* od_lw  = (const float*)d_in[16], *od_lb  = (const float*)d_in[17];
    const float* dt1_wl = (const float*)d_in[18], *dt1_wr = (const float*)d_in[19], *dt1_b = (const float*)d_in[20];
    const float* dt2_wl = (const float*)d_in[21], *dt2_wr = (const float*)d_in[22], *dt2_b = (const float*)d_in[23];
    const float* dt_lw  = (const float*)d_in[24], *dt_lb  = (const float*)d_in[25];
    const float* dec_w1 = (const float*)d_in[26], *dec_b1 = (const float*)d_in[27];
    const float* dec_w2 = (const float*)d_in[28], *dec_b2 = (const float*)d_in[29];

    hipMemsetAsync(I + I_CNT_DT, 0, (NDT + NOD) * sizeof(int), stream);

    // CSR build
    count_edges<<<(NE1 / 4 + 255) / 256, 256, 0, stream>>>(c1, rev_dst, I + I_CNT_DT, I + I_CNT_OD);
    scan2<<<2, 1024, 0, stream>>>(I + I_CNT_DT, I + I_RS_DT, I + I_CUR_DT,
                                  I + I_CNT_OD, I + I_RS_OD, I + I_CUR_OD);
    fill_edges<<<(NE1 / 4 + 255) / 256, 256, 0, stream>>>(r1, c1, rev_src, rev_dst,
                                                          I + I_CUR_DT, I + I_SRC_DT,
                                                          I + I_CUR_OD, I + I_SRC_OD);

    // decoder weight fusion (independent)
    fuse_dec<<<(16448 + 255) / 256, 256, 0, stream>>>(od_lw, od_lb, dt_lw, dt_lb, dec_w1, dec_b1,
                                                      W + F_WOD, W + F_WDT, W + F_BFUSE);

    // agg_x = segmean(x_dt) over ei_dt -> BUFA
    seg_mean<<<NDT, 128, 0, stream>>>(x_dt, I + I_RS_DT, I + I_SRC_DT, W + F_BUFA);
    // h  = relu(agg_x@od1_wl + x_dt@od1_wr + b); d1 = relu(agg_x@dt1_wl + x_dt@dt1_wr + b)
    sage_dual<<<(NDT + 31) / 32, 256, 0, stream>>>(W + F_BUFA, od1_wl, dt1_wl, x_dt, od1_wr, dt1_wr,
                                                   od1_b, dt1_b, W + F_BUFH, W + F_BUFD, NDT);
    // agg_h = segmean(h) over ei_rev -> AGGH
    seg_mean<<<NOD, 128, 0, stream>>>(W + F_BUFH, I + I_RS_OD, I + I_SRC_OD, W + F_AGGH);
    // od2 = relu(agg_h@od2_wl + x_od@od2_wr + b)
    sage_layer<<<(NOD + 31) / 32, 256, 0, stream>>>(W + F_AGGH, od2_wl, x_od, od2_wr, 64,
                                                    od2_b, W + F_OD2, NOD);
    // od3 = relu(agg_h@od3_wl + od2@od3_wr + b)
    sage_layer<<<(NOD + 31) / 32, 256, 0, stream>>>(W + F_AGGH, od3_wl, W + F_OD2, od3_wr, 128,
                                                    od3_b, W + F_OD3, NOD);
    // agg_d = segmean(d1) over ei_dt -> BUFA (agg_x dead)
    seg_mean<<<NDT, 128, 0, stream>>>(W + F_BUFD, I + I_RS_DT, I + I_SRC_DT, W + F_BUFA);
    // d2 = relu(agg_d@dt2_wl + d1@dt2_wr + b) -> BUFH (h dead)
    sage_layer<<<(NDT + 31) / 32, 256, 0, stream>>>(W + F_BUFA, dt2_wl, W + F_BUFD, dt2_wr, 128,
                                                    dt2_b, W + F_BUFH, NDT);
    // P_od = od3 @ Wod ; P_dt = d2 @ Wdt
    lin_gemm<<<(NOD + 63) / 64, 256, 0, stream>>>(W + F_OD3, W + F_WOD, W + F_POD, NOD);
    lin_gemm<<<(NDT + 63) / 64, 256, 0, stream>>>(W + F_BUFH, W + F_WDT, W + F_PDT, NDT);
    // decoder
    decode<<<(NEL + 255) / 256, 256, 0, stream>>>(W + F_POD, W + F_PDT, el_src, el_dst,
                                                  W + F_BFUSE, dec_w2, dec_b2, (float*)d_out);
}

// Round 6
// 380.391 us; speedup vs baseline: 1.4841x; 1.3411x over previous
//
#include <hip/hip_runtime.h>
#include <hip/hip_bf16.h>

#define NDT 30000
#define NOD 10000
#define NE1 500000
#define NE2 300000
#define NEL 200000

typedef unsigned short ushort_t;
typedef unsigned int uint_t;
typedef __attribute__((ext_vector_type(8))) short short8;
typedef __attribute__((ext_vector_type(4))) float f32x4;

// ---------------- workspace layout ----------------
// float region
static constexpr size_t F_BFUSE = 0;                         // 64
static constexpr size_t F_POD   = 64;                        // 10000*64
static constexpr size_t F_PDT   = F_POD + (size_t)NOD * 64;  // 30000*64
static constexpr size_t F_ENDF  = F_PDT + (size_t)NDT * 64;
// ushort region (base = (ushort_t*)(W + F_ENDF))
static constexpr size_t U_XDT   = 0;                          // 30000*128
static constexpr size_t U_XOD   = U_XDT + (size_t)NDT * 128;  // 10000*64
static constexpr size_t U_AGGX  = U_XOD + (size_t)NOD * 64;   // 30000*128 (agg_x, later agg_d)
static constexpr size_t U_H     = U_AGGX + (size_t)NDT * 128; // h, later d2
static constexpr size_t U_D1    = U_H + (size_t)NDT * 128;
static constexpr size_t U_AGGH  = U_D1 + (size_t)NDT * 128;   // 10000*128
static constexpr size_t U_OD2   = U_AGGH + (size_t)NOD * 128;
static constexpr size_t U_OD3   = U_OD2 + (size_t)NOD * 128;
static constexpr size_t U_WT1A  = U_OD3 + (size_t)NOD * 128;  // 128*256
static constexpr size_t U_WT1B  = U_WT1A + 32768;             // 128*256
static constexpr size_t U_WTOD2 = U_WT1B + 32768;             // 128*192
static constexpr size_t U_WTOD3 = U_WTOD2 + 24576;            // 128*256
static constexpr size_t U_WTDT2 = U_WTOD3 + 32768;            // 128*256
static constexpr size_t U_WLODT = U_WTDT2 + 32768;            // 64*128
static constexpr size_t U_WLDTT = U_WLODT + 8192;             // 64*128
static constexpr size_t U_END   = U_WLDTT + 8192;
// int region (base = int* at byte offset of U_END, kept 4B aligned)
static constexpr size_t I_CNT_DT = 0;
static constexpr size_t I_CNT_OD = 30000;
static constexpr size_t I_RS_DT  = 40000;
static constexpr size_t I_RS_OD  = 70004;
static constexpr size_t I_CUR_DT = 80008;
static constexpr size_t I_CUR_OD = 110008;
static constexpr size_t I_SRC_DT = 120008;
static constexpr size_t I_SRC_OD = 620008;

__device__ __forceinline__ ushort_t f2bf(float f) {
    uint_t u = __float_as_uint(f);
    return (ushort_t)((u + 0x7fffu + ((u >> 16) & 1u)) >> 16);
}
__device__ __forceinline__ float bf2f(uint_t lo16) { return __uint_as_float(lo16 << 16); }

// ---------------- conversions: x tables -> bf16 ----------------
__global__ __launch_bounds__(256) void conv_bf(const float* __restrict__ x_dt, const float* __restrict__ x_od,
                                               ushort_t* __restrict__ xdt_bf, ushort_t* __restrict__ xod_bf) {
    int i = blockIdx.x * 256 + threadIdx.x;
    size_t i4 = (size_t)i * 4;
    const size_t n_dt = (size_t)NDT * 128, n_od = (size_t)NOD * 64;
    if (i4 < n_dt) {
        float4 v = *(const float4*)(x_dt + i4);
        ushort4 o = { f2bf(v.x), f2bf(v.y), f2bf(v.z), f2bf(v.w) };
        *(ushort4*)(xdt_bf + i4) = o;
    } else if (i4 - n_dt < n_od) {
        size_t j = i4 - n_dt;
        float4 v = *(const float4*)(x_od + j);
        ushort4 o = { f2bf(v.x), f2bf(v.y), f2bf(v.z), f2bf(v.w) };
        *(ushort4*)(xod_bf + j) = o;
    }
}

// ---------------- prep: combined transposed bf16 weights Wt[n][k] ----------------
__global__ __launch_bounds__(256) void prep_wt(const float* od1_wl, const float* od1_wr,
                                               const float* dt1_wl, const float* dt1_wr,
                                               const float* od2_wl, const float* od2_wr,
                                               const float* od3_wl, const float* od3_wr,
                                               const float* dt2_wl, const float* dt2_wr,
                                               ushort_t* wt1a, ushort_t* wt1b, ushort_t* wtod2,
                                               ushort_t* wtod3, ushort_t* wtdt2) {
    int i = blockIdx.x * 256 + threadIdx.x;
    const float* wl; const float* wr; ushort_t* dst; int q, KT;
    if (i < 32768)       { q = i;          KT = 256; wl = od1_wl; wr = od1_wr; dst = wt1a; }
    else if (i < 65536)  { q = i - 32768;  KT = 256; wl = dt1_wl; wr = dt1_wr; dst = wt1b; }
    else if (i < 90112)  { q = i - 65536;  KT = 192; wl = od2_wl; wr = od2_wr; dst = wtod2; }
    else if (i < 122880) { q = i - 90112;  KT = 256; wl = od3_wl; wr = od3_wr; dst = wtod3; }
    else if (i < 155648) { q = i - 122880; KT = 256; wl = dt2_wl; wr = dt2_wr; dst = wtdt2; }
    else return;
    int n = q / KT, k = q - n * KT;
    float v = (k < 128) ? wl[(size_t)k * 128 + n] : wr[(size_t)(k - 128) * 128 + n];
    dst[q] = f2bf(v);
}

// ---------------- CSR build ----------------
__global__ __launch_bounds__(256) void count_edges(const int* __restrict__ c1,
                                                   const int* __restrict__ rev_dst,
                                                   int* cnt_dt, int* cnt_od) {
    int b = (blockIdx.x * 256 + threadIdx.x) * 4;
    if (b + 3 < NE1) {
        int4 v = *(const int4*)(c1 + b);
        atomicAdd(&cnt_dt[v.x], 1); atomicAdd(&cnt_dt[v.y], 1);
        atomicAdd(&cnt_dt[v.z], 1); atomicAdd(&cnt_dt[v.w], 1);
    } else {
        for (int i = b; i < NE1; i++) atomicAdd(&cnt_dt[c1[i]], 1);
    }
    if (b + 3 < NE2) {
        int4 v = *(const int4*)(rev_dst + b);
        atomicAdd(&cnt_od[v.x], 1); atomicAdd(&cnt_od[v.y], 1);
        atomicAdd(&cnt_od[v.z], 1); atomicAdd(&cnt_od[v.w], 1);
    } else if (b < NE2) {
        for (int i = b; i < NE2; i++) atomicAdd(&cnt_od[rev_dst[i]], 1);
    }
}

#define SCAN_PER 30
__global__ __launch_bounds__(1024) void scan2(const int* __restrict__ cnt_dt, int* rs_dt, int* cur_dt,
                                              const int* __restrict__ cnt_od, int* rs_od, int* cur_od) {
    const int* cnt; int* rs; int* cur; int n;
    if (blockIdx.x == 0) { cnt = cnt_dt; rs = rs_dt; cur = cur_dt; n = NDT; }
    else                 { cnt = cnt_od; rs = rs_od; cur = cur_od; n = NOD; }
    int t = threadIdx.x;
    int lane = t & 63, wave = t >> 6;
    int base = t * SCAN_PER;
    int vals[SCAN_PER];
    int sum = 0;
#pragma unroll
    for (int i = 0; i < SCAN_PER; i++) {
        int idx = base + i;
        int v = (idx < n) ? cnt[idx] : 0;
        vals[i] = sum;
        sum += v;
    }
    int x = sum;
#pragma unroll
    for (int off = 1; off < 64; off <<= 1) {
        int y = __shfl_up(x, off, 64);
        if (lane >= off) x += y;
    }
    __shared__ int wsum[16], woff[16];
    if (lane == 63) wsum[wave] = x;
    __syncthreads();
    if (t == 0) {
        int acc = 0;
#pragma unroll
        for (int w = 0; w < 16; w++) { woff[w] = acc; acc += wsum[w]; }
        rs[n] = acc;
    }
    __syncthreads();
    int excl = x - sum + woff[wave];
#pragma unroll
    for (int i = 0; i < SCAN_PER; i++) {
        int idx = base + i;
        if (idx < n) { int e = excl + vals[i]; rs[idx] = e; cur[idx] = e; }
    }
}

__global__ __launch_bounds__(256) void fill_edges(const int* __restrict__ r1, const int* __restrict__ c1,
                                                  const int* __restrict__ rev_src, const int* __restrict__ rev_dst,
                                                  int* cur_dt, int* srcs_dt, int* cur_od, int* srcs_od) {
    int b = (blockIdx.x * 256 + threadIdx.x) * 4;
    if (b + 3 < NE1) {
        int4 d = *(const int4*)(c1 + b);
        int4 s = *(const int4*)(r1 + b);
        int p0 = atomicAdd(&cur_dt[d.x], 1);
        int p1 = atomicAdd(&cur_dt[d.y], 1);
        int p2 = atomicAdd(&cur_dt[d.z], 1);
        int p3 = atomicAdd(&cur_dt[d.w], 1);
        srcs_dt[p0] = s.x; srcs_dt[p1] = s.y; srcs_dt[p2] = s.z; srcs_dt[p3] = s.w;
    } else {
        for (int i = b; i < NE1; i++) { int p = atomicAdd(&cur_dt[c1[i]], 1); srcs_dt[p] = r1[i]; }
    }
    if (b + 3 < NE2) {
        int4 d = *(const int4*)(rev_dst + b);
        int4 s = *(const int4*)(rev_src + b);
        int p0 = atomicAdd(&cur_od[d.x], 1);
        int p1 = atomicAdd(&cur_od[d.y], 1);
        int p2 = atomicAdd(&cur_od[d.z], 1);
        int p3 = atomicAdd(&cur_od[d.w], 1);
        srcs_od[p0] = s.x; srcs_od[p1] = s.y; srcs_od[p2] = s.z; srcs_od[p3] = s.w;
    } else if (b < NE2) {
        for (int i = b; i < NE2; i++) { int p = atomicAdd(&cur_od[rev_dst[i]], 1); srcs_od[p] = rev_src[i]; }
    }
}

// ---------------- segment mean over bf16 rows (128 cols), bf16 out ----------------
__global__ __launch_bounds__(64) void seg_mean_bf(const ushort_t* __restrict__ X,
                                                  const int* __restrict__ rs,
                                                  const int* __restrict__ srcs,
                                                  ushort_t* __restrict__ out) {
    int b = blockIdx.x;
    int t = threadIdx.x;             // 64 lanes, each owns cols 2t, 2t+1
    int start = rs[b], end = rs[b + 1];
    float a0 = 0.f, a1 = 0.f, b0 = 0.f, b1 = 0.f, c0 = 0.f, c1 = 0.f, d0 = 0.f, d1 = 0.f;
    int j = start;
    for (; j + 3 < end; j += 4) {
        uint_t v0 = *(const uint_t*)&X[(size_t)srcs[j]     * 128 + 2 * t];
        uint_t v1 = *(const uint_t*)&X[(size_t)srcs[j + 1] * 128 + 2 * t];
        uint_t v2 = *(const uint_t*)&X[(size_t)srcs[j + 2] * 128 + 2 * t];
        uint_t v3 = *(const uint_t*)&X[(size_t)srcs[j + 3] * 128 + 2 * t];
        a0 += bf2f(v0 & 0xffff); a1 += __uint_as_float(v0 & 0xffff0000u);
        b0 += bf2f(v1 & 0xffff); b1 += __uint_as_float(v1 & 0xffff0000u);
        c0 += bf2f(v2 & 0xffff); c1 += __uint_as_float(v2 & 0xffff0000u);
        d0 += bf2f(v3 & 0xffff); d1 += __uint_as_float(v3 & 0xffff0000u);
    }
    for (; j < end; j++) {
        uint_t v = *(const uint_t*)&X[(size_t)srcs[j] * 128 + 2 * t];
        a0 += bf2f(v & 0xffff); a1 += __uint_as_float(v & 0xffff0000u);
    }
    int deg = end - start;
    float inv = deg > 0 ? 1.f / (float)deg : 0.f;
    float s0 = ((a0 + b0) + (c0 + d0)) * inv;
    float s1 = ((a1 + b1) + (c1 + d1)) * inv;
    *(uint_t*)&out[(size_t)b * 128 + 2 * t] = (uint_t)f2bf(s0) | ((uint_t)f2bf(s1) << 16);
}

// ---------------- MFMA sage layer ----------------
// out = relu([A1|A2] @ Wt^T + bias), N=128, KT = K1+K2. Wt layout [n][k] bf16.
// Block: 32 rows x 128 cols, 4 waves; wave w: m-tile w&1, n-tiles (w>>1)*4..+4.
template <bool DUAL>
__global__ __launch_bounds__(256) void sage_mfma(
    const ushort_t* __restrict__ A1, int K1,
    const ushort_t* __restrict__ A2, int K2,
    const ushort_t* __restrict__ Wta, const ushort_t* __restrict__ Wtb,
    const float* __restrict__ ba, const float* __restrict__ bb,
    ushort_t* __restrict__ outa, ushort_t* __restrict__ outb, int M) {
    __shared__ __align__(16) ushort_t As[32 * 264];
    __shared__ __align__(16) ushort_t Wsa[128 * 40];
    __shared__ __align__(16) ushort_t Wsb[DUAL ? 128 * 40 : 8];
    const int KT = K1 + K2;
    const int AST = KT + 8;
    int t = threadIdx.x;
    int lane = t & 63, wave = t >> 6;
    int quad = lane >> 4, l16 = lane & 15;
    int mtile = wave & 1, nquad = wave >> 1;
    int mb = blockIdx.x * 32;

    // stage A (combined [A1|A2]), rows clamped
    int c1n = 32 * (K1 >> 3);
    for (int c = t; c < c1n; c += 256) {
        int row = c / (K1 >> 3), k8 = (c % (K1 >> 3)) * 8;
        int m = mb + row; if (m >= M) m = M - 1;
        *(short8*)&As[row * AST + k8] = *(const short8*)&A1[(size_t)m * K1 + k8];
    }
    int c2n = 32 * (K2 >> 3);
    for (int c = t; c < c2n; c += 256) {
        int row = c / (K2 >> 3), k8 = (c % (K2 >> 3)) * 8;
        int m = mb + row; if (m >= M) m = M - 1;
        *(short8*)&As[row * AST + K1 + k8] = *(const short8*)&A2[(size_t)m * K2 + k8];
    }

    f32x4 acca[4] = {};
    f32x4 accb[4] = {};
    for (int kc = 0; kc < KT; kc += 32) {
        __syncthreads();
        for (int c = t; c < 512; c += 256) {   // 128 n x 32 k chunk
            int n = c >> 2, k8 = (c & 3) * 8;
            *(short8*)&Wsa[n * 40 + k8] = *(const short8*)&Wta[(size_t)n * KT + kc + k8];
            if (DUAL)
                *(short8*)&Wsb[n * 40 + k8] = *(const short8*)&Wtb[(size_t)n * KT + kc + k8];
        }
        __syncthreads();
        short8 af = *(const short8*)&As[(mtile * 16 + l16) * AST + kc + quad * 8];
#pragma unroll
        for (int nt = 0; nt < 4; nt++) {
            int n = (nquad * 4 + nt) * 16 + l16;
            short8 bfr = *(const short8*)&Wsa[n * 40 + quad * 8];
            acca[nt] = __builtin_amdgcn_mfma_f32_16x16x32_bf16(af, bfr, acca[nt], 0, 0, 0);
            if (DUAL) {
                short8 bfr2 = *(const short8*)&Wsb[n * 40 + quad * 8];
                accb[nt] = __builtin_amdgcn_mfma_f32_16x16x32_bf16(af, bfr2, accb[nt], 0, 0, 0);
            }
        }
    }
    int mrow = mb + mtile * 16 + quad * 4;
#pragma unroll
    for (int nt = 0; nt < 4; nt++) {
        int n = (nquad * 4 + nt) * 16 + l16;
        float bva = ba[n];
        float bvb = DUAL ? bb[n] : 0.f;
#pragma unroll
        for (int r = 0; r < 4; r++) {
            int m = mrow + r;
            if (m < M) {
                outa[(size_t)m * 128 + n] = f2bf(fmaxf(acca[nt][r] + bva, 0.f));
                if (DUAL) outb[(size_t)m * 128 + n] = f2bf(fmaxf(accb[nt][r] + bvb, 0.f));
            }
        }
    }
}

// ---------------- MFMA linear: out[M][64] f32 = A[M][128] bf16 @ Wt[64][128] ----------------
__global__ __launch_bounds__(256) void lin_mfma(const ushort_t* __restrict__ A,
                                                const ushort_t* __restrict__ Wt,
                                                float* __restrict__ out, int M) {
    __shared__ __align__(16) ushort_t As[64 * 136];
    __shared__ __align__(16) ushort_t Ws[64 * 40];
    int t = threadIdx.x;
    int lane = t & 63, wave = t >> 6;
    int quad = lane >> 4, l16 = lane & 15;
    int mb = blockIdx.x * 64;
    for (int c = t; c < 1024; c += 256) {
        int row = c >> 4, k8 = (c & 15) * 8;
        int m = mb + row; if (m >= M) m = M - 1;
        *(short8*)&As[row * 136 + k8] = *(const short8*)&A[(size_t)m * 128 + k8];
    }
    f32x4 acc[4] = {};
    for (int kc = 0; kc < 128; kc += 32) {
        __syncthreads();
        for (int c = t; c < 256; c += 256) {
            int n = c >> 2, k8 = (c & 3) * 8;
            *(short8*)&Ws[n * 40 + k8] = *(const short8*)&Wt[(size_t)n * 128 + kc + k8];
        }
        __syncthreads();
        short8 af = *(const short8*)&As[(wave * 16 + l16) * 136 + kc + quad * 8];
#pragma unroll
        for (int nt = 0; nt < 4; nt++) {
            short8 bfr = *(const short8*)&Ws[(nt * 16 + l16) * 40 + quad * 8];
            acc[nt] = __builtin_amdgcn_mfma_f32_16x16x32_bf16(af, bfr, acc[nt], 0, 0, 0);
        }
    }
    int mrow = mb + wave * 16 + quad * 4;
#pragma unroll
    for (int nt = 0; nt < 4; nt++) {
        int n = nt * 16 + l16;
#pragma unroll
        for (int r = 0; r < 4; r++) {
            int m = mrow + r;
            if (m < M) out[(size_t)m * 64 + n] = acc[nt][r];
        }
    }
}

// ---------------- decoder weight fusion (bf16 transposed outputs) ----------------
__global__ __launch_bounds__(256) void fuse_dec(const float* __restrict__ od_lw, const float* __restrict__ od_lb,
                                                const float* __restrict__ dt_lw, const float* __restrict__ dt_lb,
                                                const float* __restrict__ w1, const float* __restrict__ b1,
                                                ushort_t* wodt, ushort_t* wdtt, float* bfuse) {
    int i = blockIdx.x * 256 + threadIdx.x;
    if (i < 8192) {
        int r = i >> 6, p = i & 63;
        float s = 0.f;
        for (int j = 0; j < 64; j++) s = fmaf(od_lw[r * 64 + j], w1[j * 64 + p], s);
        wodt[p * 128 + r] = f2bf(s);
    } else if (i < 16384) {
        int q = i - 8192, r = q >> 6, p = q & 63;
        float s = 0.f;
        for (int j = 0; j < 64; j++) s = fmaf(dt_lw[r * 64 + j], w1[(64 + j) * 64 + p], s);
        wdtt[p * 128 + r] = f2bf(s);
    } else if (i < 16448) {
        int p = i - 16384;
        float s = b1[p];
        for (int j = 0; j < 64; j++) {
            s = fmaf(od_lb[j], w1[j * 64 + p], s);
            s = fmaf(dt_lb[j], w1[(64 + j) * 64 + p], s);
        }
        bfuse[p] = s;
    }
}

// ---------------- decoder (f32 output) ----------------
__global__ __launch_bounds__(256) void decode(const float* __restrict__ P_od, const float* __restrict__ P_dt,
                                              const int* __restrict__ el_src, const int* __restrict__ el_dst,
                                              const float* __restrict__ bfuse, const float* __restrict__ w2,
                                              const float* __restrict__ b2v, float* __restrict__ out) {
    __shared__ __align__(16) float bf[64];
    __shared__ __align__(16) float w2s[64];
    int t = threadIdx.x;
    if (t < 64) { bf[t] = bfuse[t]; w2s[t] = w2[t]; }
    __syncthreads();
    int e = blockIdx.x * 256 + t;
    if (e >= NEL) return;
    const float4* po = (const float4*)(P_od + (size_t)el_src[e] * 64);
    const float4* pt = (const float4*)(P_dt + (size_t)el_dst[e] * 64);
    float acc = 0.f;
#pragma unroll 4
    for (int c = 0; c < 16; c++) {
        float4 a = po[c], b = pt[c];
        float4 bb = *(const float4*)&bf[c * 4];
        float4 ww = *(const float4*)&w2s[c * 4];
        acc = fmaf(fmaxf(a.x + b.x + bb.x, 0.f), ww.x, acc);
        acc = fmaf(fmaxf(a.y + b.y + bb.y, 0.f), ww.y, acc);
        acc = fmaf(fmaxf(a.z + b.z + bb.z, 0.f), ww.z, acc);
        acc = fmaf(fmaxf(a.w + b.w + bb.w, 0.f), ww.w, acc);
    }
    float z = acc + b2v[0];
    out[e] = 1.f / (1.f + __expf(-z));
}

// ---------------- launch ----------------
extern "C" void kernel_launch(void* const* d_in, const int* in_sizes, int n_in,
                              void* d_out, int out_size, void* d_ws, size_t ws_size,
                              hipStream_t stream) {
    float* W = (float*)d_ws;
    ushort_t* U = (ushort_t*)(W + F_ENDF);
    int* I = (int*)(U + U_END);

    const float* x_dt   = (const float*)d_in[0];
    const float* x_od   = (const float*)d_in[1];
    const int* ei       = (const int*)d_in[2];
    const int* r1 = ei;
    const int* c1 = ei + NE1;
    const int* rev_src  = (const int*)d_in[3];
    const int* rev_dst  = (const int*)d_in[4];
    const int* el_src   = (const int*)d_in[5];
    const int* el_dst   = (const int*)d_in[6];
    const float* od1_wl = (const float*)d_in[7],  *od1_wr = (const float*)d_in[8],  *od1_b = (const float*)d_in[9];
    const float* od2_wl = (const float*)d_in[10], *od2_wr = (const float*)d_in[11], *od2_b = (const float*)d_in[12];
    const float* od3_wl = (const float*)d_in[13], *od3_wr = (const float*)d_in[14], *od3_b = (const float*)d_in[15];
    const float* od_lw  = (const float*)d_in[16], *od_lb  = (const float*)d_in[17];
    const float* dt1_wl = (const float*)d_in[18], *dt1_wr = (const float*)d_in[19], *dt1_b = (const float*)d_in[20];
    const float* dt2_wl = (const float*)d_in[21], *dt2_wr = (const float*)d_in[22], *dt2_b = (const float*)d_in[23];
    const float* dt_lw  = (const float*)d_in[24], *dt_lb  = (const float*)d_in[25];
    const float* dec_w1 = (const float*)d_in[26], *dec_b1 = (const float*)d_in[27];
    const float* dec_w2 = (const float*)d_in[28], *dec_b2 = (const float*)d_in[29];

    hipMemsetAsync(I + I_CNT_DT, 0, (NDT + NOD) * sizeof(int), stream);

    // prep: bf16 x tables, transposed weights, CSR, decoder fusion
    conv_bf<<<((NDT * 128 + NOD * 64) / 4 + 255) / 256, 256, 0, stream>>>(x_dt, x_od, U + U_XDT, U + U_XOD);
    prep_wt<<<(155648 + 255) / 256, 256, 0, stream>>>(od1_wl, od1_wr, dt1_wl, dt1_wr, od2_wl, od2_wr,
                                                      od3_wl, od3_wr, dt2_wl, dt2_wr,
                                                      U + U_WT1A, U + U_WT1B, U + U_WTOD2, U + U_WTOD3, U + U_WTDT2);
    count_edges<<<(NE1 / 4 + 255) / 256, 256, 0, stream>>>(c1, rev_dst, I + I_CNT_DT, I + I_CNT_OD);
    scan2<<<2, 1024, 0, stream>>>(I + I_CNT_DT, I + I_RS_DT, I + I_CUR_DT,
                                  I + I_CNT_OD, I + I_RS_OD, I + I_CUR_OD);
    fill_edges<<<(NE1 / 4 + 255) / 256, 256, 0, stream>>>(r1, c1, rev_src, rev_dst,
                                                          I + I_CUR_DT, I + I_SRC_DT,
                                                          I + I_CUR_OD, I + I_SRC_OD);
    fuse_dec<<<(16448 + 255) / 256, 256, 0, stream>>>(od_lw, od_lb, dt_lw, dt_lb, dec_w1, dec_b1,
                                                      U + U_WLODT, U + U_WLDTT, W + F_BFUSE);

    // agg_x = segmean(x_dt)
    seg_mean_bf<<<NDT, 64, 0, stream>>>(U + U_XDT, I + I_RS_DT, I + I_SRC_DT, U + U_AGGX);
    // h, d1 (dual MFMA)
    sage_mfma<true><<<(NDT + 31) / 32, 256, 0, stream>>>(U + U_AGGX, 128, U + U_XDT, 128,
                                                         U + U_WT1A, U + U_WT1B, od1_b, dt1_b,
                                                         U + U_H, U + U_D1, NDT);
    // agg_h = segmean(h) over rev graph
    seg_mean_bf<<<NOD, 64, 0, stream>>>(U + U_H, I + I_RS_OD, I + I_SRC_OD, U + U_AGGH);
    // od2 = relu(agg_h@od2_wl + x_od@od2_wr + b), K2=64
    sage_mfma<false><<<(NOD + 31) / 32, 256, 0, stream>>>(U + U_AGGH, 128, U + U_XOD, 64,
                                                          U + U_WTOD2, nullptr, od2_b, nullptr,
                                                          U + U_OD2, nullptr, NOD);
    // od3 = relu(agg_h@od3_wl + od2@od3_wr + b)
    sage_mfma<false><<<(NOD + 31) / 32, 256, 0, stream>>>(U + U_AGGH, 128, U + U_OD2, 128,
                                                          U + U_WTOD3, nullptr, od3_b, nullptr,
                                                          U + U_OD3, nullptr, NOD);
    // agg_d = segmean(d1) -> AGGX (agg_x dead)
    seg_mean_bf<<<NDT, 64, 0, stream>>>(U + U_D1, I + I_RS_DT, I + I_SRC_DT, U + U_AGGX);
    // d2 = relu(agg_d@dt2_wl + d1@dt2_wr + b) -> U_H (h dead)
    sage_mfma<false><<<(NDT + 31) / 32, 256, 0, stream>>>(U + U_AGGX, 128, U + U_D1, 128,
                                                          U + U_WTDT2, nullptr, dt2_b, nullptr,
                                                          U + U_H, nullptr, NDT);
    // P tables
    lin_mfma<<<(NOD + 63) / 64, 256, 0, stream>>>(U + U_OD3, U + U_WLODT, W + F_POD, NOD);
    lin_mfma<<<(NDT + 63) / 64, 256, 0, stream>>>(U + U_H, U + U_WLDTT, W + F_PDT, NDT);
    // decoder
    decode<<<(NEL + 255) / 256, 256, 0, stream>>>(W + F_POD, W + F_PDT, el_src, el_dst,
                                                  W + F_BFUSE, dec_w2, dec_b2, (float*)d_out);
}